// Round 1
// baseline (321.795 us; speedup 1.0000x reference)
//
#include <hip/hip_runtime.h>

// Problem constants
#define NPX    2097152                // 4*512*1024 pixels per head
#define NPX4   (NPX/4)
#define CH_STR 8192                   // 64*128
#define IMG_STR 155648                // 19*8192

// Workspace: prob[2*NPX] floats at ws start, control region after.
#define OFF_CTL   (2ull*NPX*4)
// ctl layout in u32 units
#define CTL_HIST    0                   // [3 levels][2 heads][4096] = 24576
#define CTL_BAR     24576               // u[2] software grid barrier (cnt, gen)
#define CTL_PREFIX  24578               // u[2]
#define CTL_KREM    24580               // u[2]
#define CTL_THR     24582               // f[2]
#define CTL_PPSUM   24584               // f[2*2048]
#define CTL_PPCNT   28680               // u[2*2048]
#define CTL_OPSUM   32776               // f[2*256]
#define CTL_OPCNT   33288               // u[2*256]
#define CTL_BPS     33800               // f[512*2]
#define CTL_BPC     34824               // u[512*2]
#define CTL_CNT     35848               // u[1] completion counter (pass1)
#define CTL_FLAG    35849               // u[1] magic flag: fast/slow/garbage

#define MAGIC_FAST 0x3A9C67E5u
#define MAGIC_SLOW 0x3A9C67E6u
#define GRID_P1    4608u

// ---------------------------------------------------------------------------
// Pass 1: blocks [0,4096) = OHEM, one block per output row; blocks
// [4096,4608) = boundary BCE. Hot math is the measured-best R6 variant,
// bit-identical. NEW: last-finishing block (completion counter) performs the
// fast-path decide + boundary combine + out[0] write, then publishes a magic
// flag so finish_all can early-exit. Fallbacks: if the finisher never fires
// (lost increments from a pathological init race) the flag stays garbage and
// finish_all runs its full (unchanged) logic — correctness never depends on
// dispatch order or workspace poison contents.
// ---------------------------------------------------------------------------
__global__ __launch_bounds__(256) void fused_pass1(
    const float* __restrict__ mp, const float* __restrict__ cp,
    const float* __restrict__ bp, const int* __restrict__ seg,
    const float* __restrict__ bg,
    float* __restrict__ probA, float* __restrict__ ppsum, unsigned* __restrict__ ppcnt,
    float* __restrict__ bps, unsigned* __restrict__ bpc, unsigned* __restrict__ bar,
    unsigned* __restrict__ cnt, unsigned* __restrict__ flag,
    float* __restrict__ out)
{
    __shared__ float2 erow[19 * 128];          // 19.5 KB (reused as finisher scratch)
    __shared__ float rf[4]; __shared__ unsigned ru[4];
    __shared__ float rf2[4]; __shared__ unsigned ru2[4];
    __shared__ unsigned amLast;
    __shared__ float Pb[4], Nb[4]; __shared__ unsigned PCb[4], NCb[4];
    int bk = blockIdx.x;
    int tid = threadIdx.x;

    if (bk == 0 && tid < 2) bar[tid] = 0u;     // init software barrier (slow path)
    if (bk == 0 && tid == 0)                    // init completion counter
        __hip_atomic_store(cnt, 0u, __ATOMIC_RELAXED, __HIP_MEMORY_SCOPE_AGENT);

    if (bk < 4096) {
        int head = bk >> 11;
        int task = bk & 2047;                  // 2048 rows (4 samples * 512)
        int b = task >> 9;
        int y = task & 511;
        const float* pred = head ? cp : mp;

        float fy = (float)y * (63.0f / 511.0f);
        int y0 = min((int)fy, 63);
        int y1 = min(y0 + 1, 63);
        float wy = fy - (float)y0;

        const float* r0 = pred + (size_t)b * IMG_STR + y0 * 128;
        const float* r1 = pred + (size_t)b * IMG_STR + y1 * 128;
        for (int i = tid; i < 2432; i += 256) {      // 19*128
            int c = i >> 7, x = i & 127;
            float v0 = r0[c * CH_STR + x];
            float v1 = r1[c * CH_STR + x];
            float e = fmaf(wy, v1 - v0, v0);
            erow[c * 128 + x].x = e;
            if (x > 0)    erow[c * 128 + x - 1].y = e;
            if (x == 127) erow[c * 128 + 127].y = e;   // pad; weight is 0 there
        }
        __syncthreads();

        int xb = tid << 2;
        int P = (b * 512 + y) * 1024 + xb;           // per-head pixel index
        int4 t4 = *(const int4*)(seg + P);
        int t[4] = {t4.x, t4.y, t4.z, t4.w};

        float fx0 = (float)xb * (127.0f / 1023.0f);
        int X = min((int)fx0, 126);                  // taps e[X], e[X+1], e[X+2]
        float wA[4], wB[4], wC[4];
#pragma unroll
        for (int dx = 0; dx < 4; ++dx) {
            float fx = (float)(xb + dx) * (127.0f / 1023.0f);
            int x0 = min((int)fx, 127);
            float wx = fx - (float)x0;
            bool sm = (x0 == X);
            wA[dx] = sm ? (1.0f - wx) : 0.0f;        // weight on e[X]   (eA.x)
            wB[dx] = sm ? wx : (1.0f - wx);          // weight on e[X+1] (eA.y)
            wC[dx] = sm ? 0.0f : wx;                 // weight on e[X+2] (eB.y)
        }

        float s[4] = {0.f, 0.f, 0.f, 0.f};
        for (int c = 0; c < 19; ++c) {
            float2 eA = erow[c * 128 + X];           // (e[X],   e[X+1])
            float2 eB = erow[c * 128 + X + 1];       // (e[X+1], e[X+2])
#pragma unroll
            for (int dx = 0; dx < 4; ++dx) {
                float l = fmaf(eA.x, wA[dx], fmaf(eA.y, wB[dx], eB.y * wC[dx]));
                s[dx] += __expf(l);
            }
        }

        float fs = 0.f; unsigned ic = 0;
        float pr[4];
#pragma unroll
        for (int dx = 0; dx < 4; ++dx) {
            bool valid = (t[dx] != 255);
            int tc = valid ? t[dx] : 0;
            float2 eA = erow[tc * 128 + X];
            float2 eB = erow[tc * 128 + X + 1];
            float lt = fmaf(eA.x, wA[dx], fmaf(eA.y, wB[dx], eB.y * wC[dx]));  // bit-identical
            float ls = __logf(s[dx]);
            float n  = ls - lt;                      // nll at target
            float p  = fminf(__expf(-n), 1.0f);
            pr[dx] = valid ? p : 1.0f;               // mask_prob (matches reference)
            if (valid && p <= 0.7f) { fs += n; ic++; }
        }
        *(float4*)(probA + (size_t)head * NPX + P) = make_float4(pr[0], pr[1], pr[2], pr[3]);

        for (int o = 32; o; o >>= 1) {
            fs += __shfl_down(fs, o, 64);
            ic += (unsigned)__shfl_down((int)ic, o, 64);
        }
        int wave = tid >> 6, lane = tid & 63;
        if (lane == 0) { rf[wave] = fs; ru[wave] = ic; }
        __syncthreads();
        if (tid == 0) {
            ppsum[head * 2048 + task] = rf[0] + rf[1] + rf[2] + rf[3];
            ppcnt[head * 2048 + task] = ru[0] + ru[1] + ru[2] + ru[3];
        }
    } else {
        // -------- boundary BCE --------
        int bb = bk - 4096;                   // [0,512)
        int b  = bb >> 7;                     // 128 blocks per sample
        int blk = bb & 127;
        float psum = 0.f, nsum = 0.f; unsigned pc = 0, nc = 0;

        for (int g = blk * 256 + tid; g < 131072; g += 128 * 256) {
            int P = g << 2;
            int y = P >> 10, xb = P & 1023;

            float fy = (float)y * (63.0f / 511.0f);
            int y0 = min((int)fy, 63);
            int y1 = min(y0 + 1, 63);
            float wy = fy - (float)y0;

            const float* r0 = bp + b * 8192 + y0 * 128;
            const float* r1 = bp + b * 8192 + y1 * 128;
            float fx0 = (float)xb * (127.0f / 1023.0f);
            int X  = min((int)fx0, 126);
            int X2 = min(X + 2, 127);
            float c0 = r0[X], c1 = r0[X + 1], c2 = r0[X2];
            float d0 = r1[X], d1 = r1[X + 1], d2 = r1[X2];
            float e0 = fmaf(wy, d0 - c0, c0);
            float e1 = fmaf(wy, d1 - c1, c1);
            float e2 = fmaf(wy, d2 - c2, c2);

            float4 t4 = *(const float4*)(bg + (size_t)b * 524288 + P);
            float tv[4] = {t4.x, t4.y, t4.z, t4.w};

#pragma unroll
            for (int dx = 0; dx < 4; ++dx) {
                float fx = (float)(xb + dx) * (127.0f / 1023.0f);
                int x0 = min((int)fx, 127);
                int x1 = min(x0 + 1, 127);
                float wx = fx - (float)x0;
                float a0 = (x0 == X)     ? e0 : e1;
                float a1 = (x1 == X + 1) ? e1 : e2;
                float p  = fmaf(wx, a1 - a0, a0);
                bool isp = (tv[dx] == 1.0f);
                bool isn = (tv[dx] == 0.0f);
                float q = isp ? p : 1.0f - p;
                float l = fmaxf(__logf(q), -100.0f);
                if (isp) { pc++; psum -= l; }
                if (isn) { nc++; nsum -= l; }
            }
        }
        for (int o = 32; o; o >>= 1) {
            psum += __shfl_down(psum, o, 64);
            nsum += __shfl_down(nsum, o, 64);
            pc   += (unsigned)__shfl_down((int)pc, o, 64);
            nc   += (unsigned)__shfl_down((int)nc, o, 64);
        }
        int wave = tid >> 6, lane = tid & 63;
        if (lane == 0) { rf[wave] = psum; rf2[wave] = nsum; ru[wave] = pc; ru2[wave] = nc; }
        __syncthreads();
        if (tid == 0) {
            bps[2 * bb]     = rf[0] + rf[1] + rf[2] + rf[3];
            bps[2 * bb + 1] = rf2[0] + rf2[1] + rf2[2] + rf2[3];
            bpc[2 * bb]     = ru[0] + ru[1] + ru[2] + ru[3];
            bpc[2 * bb + 1] = ru2[0] + ru2[1] + ru2[2] + ru2[3];
        }
    }

    // ---------------- last-block fused finisher (fast path only) ----------------
    __syncthreads();                           // block's global stores are drained
    if (tid == 0) {
        __threadfence();                       // release: flush this block's stores
        unsigned old = __hip_atomic_fetch_add(cnt, 1u, __ATOMIC_ACQ_REL,
                                              __HIP_MEMORY_SCOPE_AGENT);
        amLast = (old == GRID_P1 - 1u) ? 1u : 0u;
    }
    __syncthreads();
    if (!amLast) return;
    __threadfence();                           // acquire: invalidate caches, read fresh

    // ---- decide (identical FP order to finish_all's redundant decide) ----
    float s0 = 0.f, s1 = 0.f; unsigned c0 = 0u, c1 = 0u;
    for (int i = tid; i < 2048; i += 256) {
        s0 += ppsum[i];        c0 += ppcnt[i];
        s1 += ppsum[2048 + i]; c1 += ppcnt[2048 + i];
    }
    for (int o = 32; o; o >>= 1) {
        s0 += __shfl_down(s0, o, 64); s1 += __shfl_down(s1, o, 64);
        c0 += (unsigned)__shfl_down((int)c0, o, 64);
        c1 += (unsigned)__shfl_down((int)c1, o, 64);
    }
    int wv = tid >> 6, ln = tid & 63;
    if (ln == 0) { rf[wv] = s0; rf2[wv] = s1; ru[wv] = c0; ru2[wv] = c1; }
    __syncthreads();
    float S0 = rf[0] + rf[1] + rf[2] + rf[3];
    float S1 = rf2[0] + rf2[1] + rf2[2] + rf2[3];
    unsigned C0 = ru[0] + ru[1] + ru[2] + ru[3];
    unsigned C1 = ru2[0] + ru2[1] + ru2[2] + ru2[3];
    bool fast = (C0 >= 100000u) && (C1 >= 100000u);

    if (fast) {
        // boundary combine — same tree algorithm as combine_out, scratch in erow
        float*    lf = (float*)erow;
        unsigned* lu = (unsigned*)erow + 256;
        for (int b = 0; b < 4; ++b) {
            float ps = 0.f, ns = 0.f; unsigned p_c = 0, n_c = 0;
            if (tid < 128) {
                int j = b * 128 + tid;
                ps = bps[2 * j]; ns = bps[2 * j + 1];
                p_c = bpc[2 * j]; n_c = bpc[2 * j + 1];
            }
            lf[tid] = ps; lu[tid] = p_c; __syncthreads();
            for (int o = 128; o; o >>= 1) {
                if (tid < o) { lf[tid] += lf[tid + o]; lu[tid] += lu[tid + o]; }
                __syncthreads();
            }
            if (tid == 0) { Pb[b] = lf[0]; PCb[b] = lu[0]; }
            __syncthreads();
            lf[tid] = ns; lu[tid] = n_c; __syncthreads();
            for (int o = 128; o; o >>= 1) {
                if (tid < o) { lf[tid] += lf[tid + o]; lu[tid] += lu[tid + o]; }
                __syncthreads();
            }
            if (tid == 0) { Nb[b] = lf[0]; NCb[b] = lu[0]; }
            __syncthreads();
        }
        if (tid == 0) {
            float bt = 0.f;
            for (int b = 0; b < 4; ++b) {
                float pos = (float)PCb[b], neg = (float)NCb[b];
                float val = fmaxf(pos + neg, 1.f);
                bt += (neg / val) * Pb[b] + (pos / val) * Nb[b];
            }
            float hls = S0 / fmaxf((float)C0, 1.f) + S1 / fmaxf((float)C1, 1.f);
            out[0] = hls + bt / 2097152.0f;
        }
    }
    __syncthreads();
    if (tid == 0) {
        __threadfence();                       // out[0] visible before flag
        __hip_atomic_store(flag, fast ? MAGIC_FAST : MAGIC_SLOW,
                           __ATOMIC_RELEASE, __HIP_MEMORY_SCOPE_AGENT);
    }
}

// ---------------------------------------------------------------------------
// Software grid barrier (sense-reversing), agent scope. SLOW PATH ONLY.
// ---------------------------------------------------------------------------
__device__ __forceinline__ void gbar(unsigned* bar, int tid) {
    __syncthreads();
    if (tid == 0) {
        unsigned g = __hip_atomic_load(&bar[1], __ATOMIC_RELAXED, __HIP_MEMORY_SCOPE_AGENT);
        unsigned t = __hip_atomic_fetch_add(&bar[0], 1u, __ATOMIC_ACQ_REL, __HIP_MEMORY_SCOPE_AGENT);
        if (t == 255u) {
            __hip_atomic_store(&bar[0], 0u, __ATOMIC_RELAXED, __HIP_MEMORY_SCOPE_AGENT);
            __hip_atomic_store(&bar[1], g + 1u, __ATOMIC_RELEASE, __HIP_MEMORY_SCOPE_AGENT);
        } else {
            while (__hip_atomic_load(&bar[1], __ATOMIC_ACQUIRE, __HIP_MEMORY_SCOPE_AGENT) == g)
                __builtin_amdgcn_s_sleep(8);
        }
    }
    __syncthreads();
}

// Block 0: reduce per-sample boundary partials and write the final output.
__device__ void combine_out(int tid, float headLossSum,
                            const float* __restrict__ bps, const unsigned* __restrict__ bpc,
                            float* __restrict__ out)
{
    __shared__ float lf[256]; __shared__ unsigned lu[256];
    __shared__ float Pb[4], Nb[4]; __shared__ unsigned PCb[4], NCb[4];
    for (int b = 0; b < 4; ++b) {
        float ps = 0.f, ns = 0.f; unsigned p_c = 0, n_c = 0;
        if (tid < 128) {
            int j = b * 128 + tid;
            ps = bps[2 * j]; ns = bps[2 * j + 1];
            p_c = bpc[2 * j]; n_c = bpc[2 * j + 1];
        }
        lf[tid] = ps; lu[tid] = p_c; __syncthreads();
        for (int o = 128; o; o >>= 1) {
            if (tid < o) { lf[tid] += lf[tid + o]; lu[tid] += lu[tid + o]; }
            __syncthreads();
        }
        if (tid == 0) { Pb[b] = lf[0]; PCb[b] = lu[0]; }
        __syncthreads();
        lf[tid] = ns; lu[tid] = n_c; __syncthreads();
        for (int o = 128; o; o >>= 1) {
            if (tid < o) { lf[tid] += lf[tid + o]; lu[tid] += lu[tid + o]; }
            __syncthreads();
        }
        if (tid == 0) { Nb[b] = lf[0]; NCb[b] = lu[0]; }
        __syncthreads();
    }
    if (tid == 0) {
        float bt = 0.f;
        for (int b = 0; b < 4; ++b) {
            float pos = (float)PCb[b], neg = (float)NCb[b];
            float val = fmaxf(pos + neg, 1.f);
            bt += (neg / val) * Pb[b] + (pos / val) * Nb[b];
        }
        out[0] = headLossSum + bt / 2097152.0f;
    }
}

// ---------------------------------------------------------------------------
// Finisher (regular launch, 256 blocks). NEW: early-exit when pass1's fused
// finisher already handled the fast path (magic flag). Any other flag value
// (slow magic, or garbage because the fused finisher didn't fire) falls
// through to the full original logic, which is self-sufficient.
// ---------------------------------------------------------------------------
__global__ __launch_bounds__(256) void finish_all(
    const float* __restrict__ probA, const int* __restrict__ seg,
    const float* __restrict__ ppsum, const unsigned* __restrict__ ppcnt,
    const float* __restrict__ bps, const unsigned* __restrict__ bpc,
    unsigned* __restrict__ hist, unsigned* __restrict__ bar,
    unsigned* __restrict__ prefix, unsigned* __restrict__ krem,
    float* __restrict__ thr,
    float* __restrict__ opsum, unsigned* __restrict__ opcnt,
    unsigned* __restrict__ flag,
    float* __restrict__ out)
{
    if (__hip_atomic_load(flag, __ATOMIC_ACQUIRE, __HIP_MEMORY_SCOPE_AGENT) == MAGIC_FAST)
        return;                               // fast path fully handled in pass1

    int tid = threadIdx.x, blk = blockIdx.x;
    int wave = tid >> 6, lane = tid & 63;

    // ---- redundant decide ----
    float s0 = 0.f, s1 = 0.f; unsigned c0 = 0u, c1 = 0u;
    for (int i = tid; i < 2048; i += 256) {
        s0 += ppsum[i];        c0 += ppcnt[i];
        s1 += ppsum[2048 + i]; c1 += ppcnt[2048 + i];
    }
    for (int o = 32; o; o >>= 1) {
        s0 += __shfl_down(s0, o, 64); s1 += __shfl_down(s1, o, 64);
        c0 += (unsigned)__shfl_down((int)c0, o, 64);
        c1 += (unsigned)__shfl_down((int)c1, o, 64);
    }
    __shared__ float ws0[4], ws1[4]; __shared__ unsigned wc0[4], wc1[4];
    if (lane == 0) { ws0[wave] = s0; ws1[wave] = s1; wc0[wave] = c0; wc1[wave] = c1; }
    __syncthreads();
    float S0 = ws0[0] + ws0[1] + ws0[2] + ws0[3];
    float S1 = ws1[0] + ws1[1] + ws1[2] + ws1[3];
    unsigned C0 = wc0[0] + wc0[1] + wc0[2] + wc0[3];
    unsigned C1 = wc1[0] + wc1[1] + wc1[2] + wc1[3];
    bool done0 = C0 >= 100000u, done1 = C1 >= 100000u;

    if (done0 && done1) {        // fast path fallback: thr = 0.7 exactly for both heads
        if (blk == 0)
            combine_out(tid, S0 / fmaxf((float)C0, 1.f) + S1 / fmaxf((float)C1, 1.f),
                        bps, bpc, out);
        return;
    }

    // ---------------- slow path: exact radix select over float bits ----------------
    __shared__ unsigned hsh[4096];
    __shared__ unsigned cpre[257];
    unsigned doneMask = (done0 ? 1u : 0u) | (done1 ? 2u : 0u);

    for (int i = blk * 256 + tid; i < 24576; i += 65536) hist[i] = 0u;
    gbar(bar, tid);

    for (int lvl = 0; lvl < 3; ++lvl) {
        unsigned* hl = hist + lvl * 8192;
        for (int h = 0; h < 2; ++h) {
            if (doneMask & (1u << h)) continue;
            unsigned pre = (lvl == 0) ? 0u : prefix[h];
            for (int i = tid; i < 4096; i += 256) hsh[i] = 0u;
            __syncthreads();
            const float4* prob = (const float4*)(probA + (size_t)h * NPX);
            for (int i = blk * 256 + tid; i < NPX4; i += 65536) {
                float4 p = prob[i];
                unsigned u[4] = {__float_as_uint(p.x), __float_as_uint(p.y),
                                 __float_as_uint(p.z), __float_as_uint(p.w)};
#pragma unroll
                for (int k = 0; k < 4; ++k) {
                    unsigned bv = u[k];
                    if (lvl == 0)      atomicAdd(&hsh[bv >> 18], 1u);
                    else if (lvl == 1) { if ((bv >> 18) == pre) atomicAdd(&hsh[(bv >> 6) & 0xFFFu], 1u); }
                    else               { if ((bv >> 6) == pre) atomicAdd(&hsh[bv & 63u], 1u); }
                }
            }
            __syncthreads();
            for (int i = tid; i < 4096; i += 256) {
                unsigned v = hsh[i];
                if (v) atomicAdd(&hl[h * 4096 + i], v);
            }
            __syncthreads();
        }
        gbar(bar, tid);
        if (blk == 0) {
            int bins = (lvl == 2) ? 64 : 4096;
            for (int h = 0; h < 2; ++h) {
                if (doneMask & (1u << h)) continue;
                const unsigned* hh = hl + h * 4096;
                int per = (bins + 255) >> 8;
                int base = tid * per;
                unsigned ssum = 0;
                for (int i = 0; i < per; ++i) { int idx = base + i; if (idx < bins) ssum += hh[idx]; }
                cpre[tid] = ssum; __syncthreads();
                if (tid == 0) {
                    unsigned acc = 0;
                    for (int i = 0; i < 256; ++i) { unsigned v = cpre[i]; cpre[i] = acc; acc += v; }
                    cpre[256] = acc;
                }
                __syncthreads();
                unsigned K = (lvl == 0) ? 100000u : krem[h];
                unsigned my = cpre[tid], nx = cpre[tid + 1];
                if (K > 0 && my < K && K <= nx) {
                    unsigned acc = my;
                    for (int i = 0; i < per; ++i) {
                        int idx = base + i;
                        unsigned c = (idx < bins) ? hh[idx] : 0u;
                        if (acc < K && K <= acc + c) {
                            if (lvl == 0)      { prefix[h] = (unsigned)idx; krem[h] = K - acc; }
                            else if (lvl == 1) { prefix[h] = (prefix[h] << 12) | (unsigned)idx; krem[h] = K - acc; }
                            else {
                                unsigned bitsv = (prefix[h] << 6) | (unsigned)idx;
                                thr[h] = fmaxf(0.7f, __uint_as_float(bitsv));
                            }
                            break;
                        }
                        acc += c;
                    }
                }
                __syncthreads();
            }
        }
        gbar(bar, tid);
    }

    // masked reduce with exact thr (nll recomputed as -log(prob))
    for (int h = 0; h < 2; ++h) {
        if (doneMask & (1u << h)) continue;
        float th = thr[h];
        const float4* prob = (const float4*)(probA + (size_t)h * NPX);
        const int4*   sg4  = (const int4*)seg;
        float fs = 0.f; unsigned ic = 0;
        for (int i = blk * 256 + tid; i < NPX4; i += 65536) {
            float4 p = prob[i]; int4 tt = sg4[i];
            if (tt.x != 255 && p.x <= th) { fs -= __logf(p.x); ic++; }
            if (tt.y != 255 && p.y <= th) { fs -= __logf(p.y); ic++; }
            if (tt.z != 255 && p.z <= th) { fs -= __logf(p.z); ic++; }
            if (tt.w != 255 && p.w <= th) { fs -= __logf(p.w); ic++; }
        }
        for (int o = 32; o; o >>= 1) {
            fs += __shfl_down(fs, o, 64);
            ic += (unsigned)__shfl_down((int)ic, o, 64);
        }
        __shared__ float wf[4]; __shared__ unsigned wu[4];
        if (lane == 0) { wf[wave] = fs; wu[wave] = ic; }
        __syncthreads();
        if (tid == 0) {
            opsum[h * 256 + blk] = wf[0] + wf[1] + wf[2] + wf[3];
            opcnt[h * 256 + blk] = wu[0] + wu[1] + wu[2] + wu[3];
        }
        __syncthreads();
    }
    gbar(bar, tid);
    if (blk == 0) {
        __shared__ float lf2[256]; __shared__ unsigned lu2[256];
        float hls = 0.f;
        for (int h = 0; h < 2; ++h) {
            float S; unsigned C;
            if (doneMask & (1u << h)) {
                S = h ? S1 : S0; C = h ? C1 : C0;
            } else {
                lf2[tid] = opsum[h * 256 + tid]; lu2[tid] = opcnt[h * 256 + tid];
                __syncthreads();
                for (int o = 128; o; o >>= 1) {
                    if (tid < o) { lf2[tid] += lf2[tid + o]; lu2[tid] += lu2[tid + o]; }
                    __syncthreads();
                }
                S = lf2[0]; C = lu2[0];
                __syncthreads();
            }
            hls += S / fmaxf((float)C, 1.f);
        }
        combine_out(tid, hls, bps, bpc, out);
    }
}

extern "C" void kernel_launch(void* const* d_in, const int* in_sizes, int n_in,
                              void* d_out, int out_size, void* d_ws, size_t ws_size,
                              hipStream_t stream)
{
    const float* mp  = (const float*)d_in[0];
    const float* cp  = (const float*)d_in[1];
    const float* bp  = (const float*)d_in[2];
    const int*   seg = (const int*)d_in[3];
    const float* bg  = (const float*)d_in[4];
    float* out = (float*)d_out;

    char* ws = (char*)d_ws;
    float* probA = (float*)ws;
    unsigned* ctl    = (unsigned*)(ws + OFF_CTL);
    unsigned* hist   = ctl + CTL_HIST;
    unsigned* bar    = ctl + CTL_BAR;
    unsigned* prefix = ctl + CTL_PREFIX;
    unsigned* krem   = ctl + CTL_KREM;
    float*    thr    = (float*)(ctl + CTL_THR);
    float*    ppsum  = (float*)(ctl + CTL_PPSUM);
    unsigned* ppcnt  = ctl + CTL_PPCNT;
    float*    opsum  = (float*)(ctl + CTL_OPSUM);
    unsigned* opcnt  = ctl + CTL_OPCNT;
    float*    bps    = (float*)(ctl + CTL_BPS);
    unsigned* bpc    = ctl + CTL_BPC;
    unsigned* cnt    = ctl + CTL_CNT;
    unsigned* flag   = ctl + CTL_FLAG;

    fused_pass1<<<dim3(GRID_P1), 256, 0, stream>>>(mp, cp, bp, seg, bg, probA,
                                                   ppsum, ppcnt, bps, bpc, bar,
                                                   cnt, flag, out);
    finish_all<<<dim3(256), 256, 0, stream>>>(probA, seg, ppsum, ppcnt, bps, bpc,
                                              hist, bar, prefix, krem, thr,
                                              opsum, opcnt, flag, out);
}

// Round 2
// 148.285 us; speedup vs baseline: 2.1701x; 2.1701x over previous
//
#include <hip/hip_runtime.h>

// Problem constants
#define NPX    2097152                // 4*512*1024 pixels per head
#define NPX4   (NPX/4)
#define CH_STR 8192                   // 64*128
#define IMG_STR 155648                // 19*8192

// Workspace: prob[2*NPX] floats at ws start, control region after.
#define OFF_CTL   (2ull*NPX*4)
// ctl layout in u32 units
#define CTL_HIST    0                   // [3 levels][2 heads][4096] = 24576
#define CTL_BAR     24576               // u[2] software grid barrier (cnt, gen)
#define CTL_CNT     24578               // u[1] pass1 completion counter
#define CTL_FLAG    24579               // u[1] magic flag (0 = not handled)
#define CTL_PREFIX  24580               // u[2]
#define CTL_KREM    24582               // u[2]
#define CTL_THR     24584               // f[2]
#define CTL_PPSUM   24586               // f[2*2048]
#define CTL_PPCNT   28682               // u[2*2048]
#define CTL_OPSUM   32778               // f[2*256]
#define CTL_OPCNT   33290               // u[2*256]
#define CTL_BPS     33802               // f[512*2]
#define CTL_BPC     34826               // u[512*2]

#define MAGIC_FAST 0x3A9C67E5u
#define GRID_P1    4608u

// Device-coherent (cross-XCD) single-access ops: relaxed AGENT atomics compile
// to global_load/store with sc1 (write-through / L2-bypass) — NO L2 flush,
// unlike __threadfence() which emits buffer_wbl2/inv (the R1 250µs regression).
__device__ __forceinline__ void st_dev_f(float* p, float v) {
    __hip_atomic_store(p, v, __ATOMIC_RELAXED, __HIP_MEMORY_SCOPE_AGENT);
}
__device__ __forceinline__ void st_dev_u(unsigned* p, unsigned v) {
    __hip_atomic_store(p, v, __ATOMIC_RELAXED, __HIP_MEMORY_SCOPE_AGENT);
}
__device__ __forceinline__ float ld_dev_f(const float* p) {
    return __hip_atomic_load((float*)p, __ATOMIC_RELAXED, __HIP_MEMORY_SCOPE_AGENT);
}
__device__ __forceinline__ unsigned ld_dev_u(const unsigned* p) {
    return __hip_atomic_load((unsigned*)p, __ATOMIC_RELAXED, __HIP_MEMORY_SCOPE_AGENT);
}

// ---------------------------------------------------------------------------
// Pass 1: blocks [0,4096) = OHEM, one block per output row; blocks
// [4096,4608) = boundary BCE. Hot math is the measured-best R6 variant,
// bit-identical. Partials are published with sc1 stores; the last-finishing
// block (relaxed counter, no fences) re-reads them with sc1 loads in the
// EXACT FP order of finish_all's decide/combine (absmax must stay 0.0),
// writes out[0] on the fast path, and sets the magic flag. cnt/flag/bar are
// zeroed by a 16-byte hipMemsetAsync before launch — no dispatch-order or
// poison-content assumptions anywhere.
// ---------------------------------------------------------------------------
__global__ __launch_bounds__(256) void fused_pass1(
    const float* __restrict__ mp, const float* __restrict__ cp,
    const float* __restrict__ bp, const int* __restrict__ seg,
    const float* __restrict__ bg,
    float* __restrict__ probA, float* __restrict__ ppsum, unsigned* __restrict__ ppcnt,
    float* __restrict__ bps, unsigned* __restrict__ bpc,
    unsigned* __restrict__ cnt, unsigned* __restrict__ flag,
    float* __restrict__ out)
{
    __shared__ float2 erow[19 * 128];          // 19.5 KB (reused as finisher scratch)
    __shared__ float rf[4]; __shared__ unsigned ru[4];
    __shared__ float rf2[4]; __shared__ unsigned ru2[4];
    __shared__ unsigned amLast;
    __shared__ float Pb[4], Nb[4]; __shared__ unsigned PCb[4], NCb[4];
    int bk = blockIdx.x;
    int tid = threadIdx.x;

    if (bk < 4096) {
        int head = bk >> 11;
        int task = bk & 2047;                  // 2048 rows (4 samples * 512)
        int b = task >> 9;
        int y = task & 511;
        const float* pred = head ? cp : mp;

        float fy = (float)y * (63.0f / 511.0f);
        int y0 = min((int)fy, 63);
        int y1 = min(y0 + 1, 63);
        float wy = fy - (float)y0;

        const float* r0 = pred + (size_t)b * IMG_STR + y0 * 128;
        const float* r1 = pred + (size_t)b * IMG_STR + y1 * 128;
        for (int i = tid; i < 2432; i += 256) {      // 19*128
            int c = i >> 7, x = i & 127;
            float v0 = r0[c * CH_STR + x];
            float v1 = r1[c * CH_STR + x];
            float e = fmaf(wy, v1 - v0, v0);
            erow[c * 128 + x].x = e;
            if (x > 0)    erow[c * 128 + x - 1].y = e;
            if (x == 127) erow[c * 128 + 127].y = e;   // pad; weight is 0 there
        }
        __syncthreads();

        int xb = tid << 2;
        int P = (b * 512 + y) * 1024 + xb;           // per-head pixel index
        int4 t4 = *(const int4*)(seg + P);
        int t[4] = {t4.x, t4.y, t4.z, t4.w};

        float fx0 = (float)xb * (127.0f / 1023.0f);
        int X = min((int)fx0, 126);                  // taps e[X], e[X+1], e[X+2]
        float wA[4], wB[4], wC[4];
#pragma unroll
        for (int dx = 0; dx < 4; ++dx) {
            float fx = (float)(xb + dx) * (127.0f / 1023.0f);
            int x0 = min((int)fx, 127);
            float wx = fx - (float)x0;
            bool sm = (x0 == X);
            wA[dx] = sm ? (1.0f - wx) : 0.0f;        // weight on e[X]   (eA.x)
            wB[dx] = sm ? wx : (1.0f - wx);          // weight on e[X+1] (eA.y)
            wC[dx] = sm ? 0.0f : wx;                 // weight on e[X+2] (eB.y)
        }

        float s[4] = {0.f, 0.f, 0.f, 0.f};
        for (int c = 0; c < 19; ++c) {
            float2 eA = erow[c * 128 + X];           // (e[X],   e[X+1])
            float2 eB = erow[c * 128 + X + 1];       // (e[X+1], e[X+2])
#pragma unroll
            for (int dx = 0; dx < 4; ++dx) {
                float l = fmaf(eA.x, wA[dx], fmaf(eA.y, wB[dx], eB.y * wC[dx]));
                s[dx] += __expf(l);
            }
        }

        float fs = 0.f; unsigned ic = 0;
        float pr[4];
#pragma unroll
        for (int dx = 0; dx < 4; ++dx) {
            bool valid = (t[dx] != 255);
            int tc = valid ? t[dx] : 0;
            float2 eA = erow[tc * 128 + X];
            float2 eB = erow[tc * 128 + X + 1];
            float lt = fmaf(eA.x, wA[dx], fmaf(eA.y, wB[dx], eB.y * wC[dx]));  // bit-identical
            float ls = __logf(s[dx]);
            float n  = ls - lt;                      // nll at target
            float p  = fminf(__expf(-n), 1.0f);
            pr[dx] = valid ? p : 1.0f;               // mask_prob (matches reference)
            if (valid && p <= 0.7f) { fs += n; ic++; }
        }
        *(float4*)(probA + (size_t)head * NPX + P) = make_float4(pr[0], pr[1], pr[2], pr[3]);

        for (int o = 32; o; o >>= 1) {
            fs += __shfl_down(fs, o, 64);
            ic += (unsigned)__shfl_down((int)ic, o, 64);
        }
        int wave = tid >> 6, lane = tid & 63;
        if (lane == 0) { rf[wave] = fs; ru[wave] = ic; }
        __syncthreads();
        if (tid == 0) {
            st_dev_f(&ppsum[head * 2048 + task], rf[0] + rf[1] + rf[2] + rf[3]);
            st_dev_u(&ppcnt[head * 2048 + task], ru[0] + ru[1] + ru[2] + ru[3]);
        }
    } else {
        // -------- boundary BCE --------
        int bb = bk - 4096;                   // [0,512)
        int b  = bb >> 7;                     // 128 blocks per sample
        int blk = bb & 127;
        float psum = 0.f, nsum = 0.f; unsigned pc = 0, nc = 0;

        for (int g = blk * 256 + tid; g < 131072; g += 128 * 256) {
            int P = g << 2;
            int y = P >> 10, xb = P & 1023;

            float fy = (float)y * (63.0f / 511.0f);
            int y0 = min((int)fy, 63);
            int y1 = min(y0 + 1, 63);
            float wy = fy - (float)y0;

            const float* r0 = bp + b * 8192 + y0 * 128;
            const float* r1 = bp + b * 8192 + y1 * 128;
            float fx0 = (float)xb * (127.0f / 1023.0f);
            int X  = min((int)fx0, 126);
            int X2 = min(X + 2, 127);
            float c0 = r0[X], c1 = r0[X + 1], c2 = r0[X2];
            float d0 = r1[X], d1 = r1[X + 1], d2 = r1[X2];
            float e0 = fmaf(wy, d0 - c0, c0);
            float e1 = fmaf(wy, d1 - c1, c1);
            float e2 = fmaf(wy, d2 - c2, c2);

            float4 t4 = *(const float4*)(bg + (size_t)b * 524288 + P);
            float tv[4] = {t4.x, t4.y, t4.z, t4.w};

#pragma unroll
            for (int dx = 0; dx < 4; ++dx) {
                float fx = (float)(xb + dx) * (127.0f / 1023.0f);
                int x0 = min((int)fx, 127);
                int x1 = min(x0 + 1, 127);
                float wx = fx - (float)x0;
                float a0 = (x0 == X)     ? e0 : e1;
                float a1 = (x1 == X + 1) ? e1 : e2;
                float p  = fmaf(wx, a1 - a0, a0);
                bool isp = (tv[dx] == 1.0f);
                bool isn = (tv[dx] == 0.0f);
                float q = isp ? p : 1.0f - p;
                float l = fmaxf(__logf(q), -100.0f);
                if (isp) { pc++; psum -= l; }
                if (isn) { nc++; nsum -= l; }
            }
        }
        for (int o = 32; o; o >>= 1) {
            psum += __shfl_down(psum, o, 64);
            nsum += __shfl_down(nsum, o, 64);
            pc   += (unsigned)__shfl_down((int)pc, o, 64);
            nc   += (unsigned)__shfl_down((int)nc, o, 64);
        }
        int wave = tid >> 6, lane = tid & 63;
        if (lane == 0) { rf[wave] = psum; rf2[wave] = nsum; ru[wave] = pc; ru2[wave] = nc; }
        __syncthreads();
        if (tid == 0) {
            st_dev_f(&bps[2 * bb],     rf[0] + rf[1] + rf[2] + rf[3]);
            st_dev_f(&bps[2 * bb + 1], rf2[0] + rf2[1] + rf2[2] + rf2[3]);
            st_dev_u(&bpc[2 * bb],     ru[0] + ru[1] + ru[2] + ru[3]);
            st_dev_u(&bpc[2 * bb + 1], ru2[0] + ru2[1] + ru2[2] + ru2[3]);
        }
    }

    // ---------------- last-block fused finisher (fast path only) ----------------
    // tid0's sc1 partial stores are already device-visible once vmcnt drains;
    // no L2 writeback needed (contrast R1's __threadfence regression).
    __syncthreads();
    if (tid == 0) {
        asm volatile("s_waitcnt vmcnt(0)" ::: "memory");
        unsigned old = __hip_atomic_fetch_add(cnt, 1u, __ATOMIC_RELAXED,
                                              __HIP_MEMORY_SCOPE_AGENT);
        amLast = (old == GRID_P1 - 1u) ? 1u : 0u;
    }
    __syncthreads();
    if (!amLast) return;

    // ---- decide (identical FP order to finish_all's redundant decide) ----
    float s0 = 0.f, s1 = 0.f; unsigned c0 = 0u, c1 = 0u;
    for (int i = tid; i < 2048; i += 256) {
        s0 += ld_dev_f(&ppsum[i]);        c0 += ld_dev_u(&ppcnt[i]);
        s1 += ld_dev_f(&ppsum[2048 + i]); c1 += ld_dev_u(&ppcnt[2048 + i]);
    }
    for (int o = 32; o; o >>= 1) {
        s0 += __shfl_down(s0, o, 64); s1 += __shfl_down(s1, o, 64);
        c0 += (unsigned)__shfl_down((int)c0, o, 64);
        c1 += (unsigned)__shfl_down((int)c1, o, 64);
    }
    int wv = tid >> 6, ln = tid & 63;
    if (ln == 0) { rf[wv] = s0; rf2[wv] = s1; ru[wv] = c0; ru2[wv] = c1; }
    __syncthreads();
    float S0 = rf[0] + rf[1] + rf[2] + rf[3];
    float S1 = rf2[0] + rf2[1] + rf2[2] + rf2[3];
    unsigned C0 = ru[0] + ru[1] + ru[2] + ru[3];
    unsigned C1 = ru2[0] + ru2[1] + ru2[2] + ru2[3];
    bool fast = (C0 >= 100000u) && (C1 >= 100000u);

    if (fast) {
        // boundary combine — same tree algorithm/order as combine_out
        float*    lf = (float*)erow;
        unsigned* lu = (unsigned*)erow + 256;
        for (int b = 0; b < 4; ++b) {
            float ps = 0.f, ns = 0.f; unsigned p_c = 0, n_c = 0;
            if (tid < 128) {
                int j = b * 128 + tid;
                ps  = ld_dev_f(&bps[2 * j]); ns  = ld_dev_f(&bps[2 * j + 1]);
                p_c = ld_dev_u(&bpc[2 * j]); n_c = ld_dev_u(&bpc[2 * j + 1]);
            }
            lf[tid] = ps; lu[tid] = p_c; __syncthreads();
            for (int o = 128; o; o >>= 1) {
                if (tid < o) { lf[tid] += lf[tid + o]; lu[tid] += lu[tid + o]; }
                __syncthreads();
            }
            if (tid == 0) { Pb[b] = lf[0]; PCb[b] = lu[0]; }
            __syncthreads();
            lf[tid] = ns; lu[tid] = n_c; __syncthreads();
            for (int o = 128; o; o >>= 1) {
                if (tid < o) { lf[tid] += lf[tid + o]; lu[tid] += lu[tid + o]; }
                __syncthreads();
            }
            if (tid == 0) { Nb[b] = lf[0]; NCb[b] = lu[0]; }
            __syncthreads();
        }
        if (tid == 0) {
            float bt = 0.f;
            for (int b = 0; b < 4; ++b) {
                float pos = (float)PCb[b], neg = (float)NCb[b];
                float val = fmaxf(pos + neg, 1.f);
                bt += (neg / val) * Pb[b] + (pos / val) * Nb[b];
            }
            float hls = S0 / fmaxf((float)C0, 1.f) + S1 / fmaxf((float)C1, 1.f);
            out[0] = hls + bt / 2097152.0f;
            st_dev_u(flag, MAGIC_FAST);   // finish_all reads after kernel boundary
        }
    }
    // !fast: flag stays 0 (memset) -> finish_all runs its full original logic
}

// ---------------------------------------------------------------------------
// Software grid barrier (sense-reversing), agent scope. SLOW PATH ONLY.
// ---------------------------------------------------------------------------
__device__ __forceinline__ void gbar(unsigned* bar, int tid) {
    __syncthreads();
    if (tid == 0) {
        unsigned g = __hip_atomic_load(&bar[1], __ATOMIC_RELAXED, __HIP_MEMORY_SCOPE_AGENT);
        unsigned t = __hip_atomic_fetch_add(&bar[0], 1u, __ATOMIC_ACQ_REL, __HIP_MEMORY_SCOPE_AGENT);
        if (t == 255u) {
            __hip_atomic_store(&bar[0], 0u, __ATOMIC_RELAXED, __HIP_MEMORY_SCOPE_AGENT);
            __hip_atomic_store(&bar[1], g + 1u, __ATOMIC_RELEASE, __HIP_MEMORY_SCOPE_AGENT);
        } else {
            while (__hip_atomic_load(&bar[1], __ATOMIC_ACQUIRE, __HIP_MEMORY_SCOPE_AGENT) == g)
                __builtin_amdgcn_s_sleep(8);
        }
    }
    __syncthreads();
}

// Block 0: reduce per-sample boundary partials and write the final output.
__device__ void combine_out(int tid, float headLossSum,
                            const float* __restrict__ bps, const unsigned* __restrict__ bpc,
                            float* __restrict__ out)
{
    __shared__ float lf[256]; __shared__ unsigned lu[256];
    __shared__ float Pb[4], Nb[4]; __shared__ unsigned PCb[4], NCb[4];
    for (int b = 0; b < 4; ++b) {
        float ps = 0.f, ns = 0.f; unsigned p_c = 0, n_c = 0;
        if (tid < 128) {
            int j = b * 128 + tid;
            ps = bps[2 * j]; ns = bps[2 * j + 1];
            p_c = bpc[2 * j]; n_c = bpc[2 * j + 1];
        }
        lf[tid] = ps; lu[tid] = p_c; __syncthreads();
        for (int o = 128; o; o >>= 1) {
            if (tid < o) { lf[tid] += lf[tid + o]; lu[tid] += lu[tid + o]; }
            __syncthreads();
        }
        if (tid == 0) { Pb[b] = lf[0]; PCb[b] = lu[0]; }
        __syncthreads();
        lf[tid] = ns; lu[tid] = n_c; __syncthreads();
        for (int o = 128; o; o >>= 1) {
            if (tid < o) { lf[tid] += lf[tid + o]; lu[tid] += lu[tid + o]; }
            __syncthreads();
        }
        if (tid == 0) { Nb[b] = lf[0]; NCb[b] = lu[0]; }
        __syncthreads();
    }
    if (tid == 0) {
        float bt = 0.f;
        for (int b = 0; b < 4; ++b) {
            float pos = (float)PCb[b], neg = (float)NCb[b];
            float val = fmaxf(pos + neg, 1.f);
            bt += (neg / val) * Pb[b] + (pos / val) * Nb[b];
        }
        out[0] = headLossSum + bt / 2097152.0f;
    }
}

// ---------------------------------------------------------------------------
// Finisher (regular launch, 256 blocks). Early-exit when pass1's fused
// finisher already handled the fast path (magic flag). Any other flag value
// (0 from memset, since the fused finisher didn't take the fast path) falls
// through to the full original logic, which is self-sufficient.
// ---------------------------------------------------------------------------
__global__ __launch_bounds__(256) void finish_all(
    const float* __restrict__ probA, const int* __restrict__ seg,
    const float* __restrict__ ppsum, const unsigned* __restrict__ ppcnt,
    const float* __restrict__ bps, const unsigned* __restrict__ bpc,
    unsigned* __restrict__ hist, unsigned* __restrict__ bar,
    unsigned* __restrict__ prefix, unsigned* __restrict__ krem,
    float* __restrict__ thr,
    float* __restrict__ opsum, unsigned* __restrict__ opcnt,
    unsigned* __restrict__ flag,
    float* __restrict__ out)
{
    if (*flag == MAGIC_FAST)                  // kernel boundary => visible
        return;                               // fast path fully handled in pass1

    int tid = threadIdx.x, blk = blockIdx.x;
    int wave = tid >> 6, lane = tid & 63;

    // ---- redundant decide ----
    float s0 = 0.f, s1 = 0.f; unsigned c0 = 0u, c1 = 0u;
    for (int i = tid; i < 2048; i += 256) {
        s0 += ppsum[i];        c0 += ppcnt[i];
        s1 += ppsum[2048 + i]; c1 += ppcnt[2048 + i];
    }
    for (int o = 32; o; o >>= 1) {
        s0 += __shfl_down(s0, o, 64); s1 += __shfl_down(s1, o, 64);
        c0 += (unsigned)__shfl_down((int)c0, o, 64);
        c1 += (unsigned)__shfl_down((int)c1, o, 64);
    }
    __shared__ float ws0[4], ws1[4]; __shared__ unsigned wc0[4], wc1[4];
    if (lane == 0) { ws0[wave] = s0; ws1[wave] = s1; wc0[wave] = c0; wc1[wave] = c1; }
    __syncthreads();
    float S0 = ws0[0] + ws0[1] + ws0[2] + ws0[3];
    float S1 = ws1[0] + ws1[1] + ws1[2] + ws1[3];
    unsigned C0 = wc0[0] + wc0[1] + wc0[2] + wc0[3];
    unsigned C1 = wc1[0] + wc1[1] + wc1[2] + wc1[3];
    bool done0 = C0 >= 100000u, done1 = C1 >= 100000u;

    if (done0 && done1) {        // fast path fallback: thr = 0.7 exactly for both heads
        if (blk == 0)
            combine_out(tid, S0 / fmaxf((float)C0, 1.f) + S1 / fmaxf((float)C1, 1.f),
                        bps, bpc, out);
        return;
    }

    // ---------------- slow path: exact radix select over float bits ----------------
    __shared__ unsigned hsh[4096];
    __shared__ unsigned cpre[257];
    unsigned doneMask = (done0 ? 1u : 0u) | (done1 ? 2u : 0u);

    for (int i = blk * 256 + tid; i < 24576; i += 65536) hist[i] = 0u;
    gbar(bar, tid);

    for (int lvl = 0; lvl < 3; ++lvl) {
        unsigned* hl = hist + lvl * 8192;
        for (int h = 0; h < 2; ++h) {
            if (doneMask & (1u << h)) continue;
            unsigned pre = (lvl == 0) ? 0u : prefix[h];
            for (int i = tid; i < 4096; i += 256) hsh[i] = 0u;
            __syncthreads();
            const float4* prob = (const float4*)(probA + (size_t)h * NPX);
            for (int i = blk * 256 + tid; i < NPX4; i += 65536) {
                float4 p = prob[i];
                unsigned u[4] = {__float_as_uint(p.x), __float_as_uint(p.y),
                                 __float_as_uint(p.z), __float_as_uint(p.w)};
#pragma unroll
                for (int k = 0; k < 4; ++k) {
                    unsigned bv = u[k];
                    if (lvl == 0)      atomicAdd(&hsh[bv >> 18], 1u);
                    else if (lvl == 1) { if ((bv >> 18) == pre) atomicAdd(&hsh[(bv >> 6) & 0xFFFu], 1u); }
                    else               { if ((bv >> 6) == pre) atomicAdd(&hsh[bv & 63u], 1u); }
                }
            }
            __syncthreads();
            for (int i = tid; i < 4096; i += 256) {
                unsigned v = hsh[i];
                if (v) atomicAdd(&hl[h * 4096 + i], v);
            }
            __syncthreads();
        }
        gbar(bar, tid);
        if (blk == 0) {
            int bins = (lvl == 2) ? 64 : 4096;
            for (int h = 0; h < 2; ++h) {
                if (doneMask & (1u << h)) continue;
                const unsigned* hh = hl + h * 4096;
                int per = (bins + 255) >> 8;
                int base = tid * per;
                unsigned ssum = 0;
                for (int i = 0; i < per; ++i) { int idx = base + i; if (idx < bins) ssum += hh[idx]; }
                cpre[tid] = ssum; __syncthreads();
                if (tid == 0) {
                    unsigned acc = 0;
                    for (int i = 0; i < 256; ++i) { unsigned v = cpre[i]; cpre[i] = acc; acc += v; }
                    cpre[256] = acc;
                }
                __syncthreads();
                unsigned K = (lvl == 0) ? 100000u : krem[h];
                unsigned my = cpre[tid], nx = cpre[tid + 1];
                if (K > 0 && my < K && K <= nx) {
                    unsigned acc = my;
                    for (int i = 0; i < per; ++i) {
                        int idx = base + i;
                        unsigned c = (idx < bins) ? hh[idx] : 0u;
                        if (acc < K && K <= acc + c) {
                            if (lvl == 0)      { prefix[h] = (unsigned)idx; krem[h] = K - acc; }
                            else if (lvl == 1) { prefix[h] = (prefix[h] << 12) | (unsigned)idx; krem[h] = K - acc; }
                            else {
                                unsigned bitsv = (prefix[h] << 6) | (unsigned)idx;
                                thr[h] = fmaxf(0.7f, __uint_as_float(bitsv));
                            }
                            break;
                        }
                        acc += c;
                    }
                }
                __syncthreads();
            }
        }
        gbar(bar, tid);
    }

    // masked reduce with exact thr (nll recomputed as -log(prob))
    for (int h = 0; h < 2; ++h) {
        if (doneMask & (1u << h)) continue;
        float th = thr[h];
        const float4* prob = (const float4*)(probA + (size_t)h * NPX);
        const int4*   sg4  = (const int4*)seg;
        float fs = 0.f; unsigned ic = 0;
        for (int i = blk * 256 + tid; i < NPX4; i += 65536) {
            float4 p = prob[i]; int4 tt = sg4[i];
            if (tt.x != 255 && p.x <= th) { fs -= __logf(p.x); ic++; }
            if (tt.y != 255 && p.y <= th) { fs -= __logf(p.y); ic++; }
            if (tt.z != 255 && p.z <= th) { fs -= __logf(p.z); ic++; }
            if (tt.w != 255 && p.w <= th) { fs -= __logf(p.w); ic++; }
        }
        for (int o = 32; o; o >>= 1) {
            fs += __shfl_down(fs, o, 64);
            ic += (unsigned)__shfl_down((int)ic, o, 64);
        }
        __shared__ float wf[4]; __shared__ unsigned wu[4];
        if (lane == 0) { wf[wave] = fs; wu[wave] = ic; }
        __syncthreads();
        if (tid == 0) {
            opsum[h * 256 + blk] = wf[0] + wf[1] + wf[2] + wf[3];
            opcnt[h * 256 + blk] = wu[0] + wu[1] + wu[2] + wu[3];
        }
        __syncthreads();
    }
    gbar(bar, tid);
    if (blk == 0) {
        __shared__ float lf2[256]; __shared__ unsigned lu2[256];
        float hls = 0.f;
        for (int h = 0; h < 2; ++h) {
            float S; unsigned C;
            if (doneMask & (1u << h)) {
                S = h ? S1 : S0; C = h ? C1 : C0;
            } else {
                lf2[tid] = opsum[h * 256 + tid]; lu2[tid] = opcnt[h * 256 + tid];
                __syncthreads();
                for (int o = 128; o; o >>= 1) {
                    if (tid < o) { lf2[tid] += lf2[tid + o]; lu2[tid] += lu2[tid + o]; }
                    __syncthreads();
                }
                S = lf2[0]; C = lu2[0];
                __syncthreads();
            }
            hls += S / fmaxf((float)C, 1.f);
        }
        combine_out(tid, hls, bps, bpc, out);
    }
}

extern "C" void kernel_launch(void* const* d_in, const int* in_sizes, int n_in,
                              void* d_out, int out_size, void* d_ws, size_t ws_size,
                              hipStream_t stream)
{
    const float* mp  = (const float*)d_in[0];
    const float* cp  = (const float*)d_in[1];
    const float* bp  = (const float*)d_in[2];
    const int*   seg = (const int*)d_in[3];
    const float* bg  = (const float*)d_in[4];
    float* out = (float*)d_out;

    char* ws = (char*)d_ws;
    float* probA = (float*)ws;
    unsigned* ctl    = (unsigned*)(ws + OFF_CTL);
    unsigned* hist   = ctl + CTL_HIST;
    unsigned* bar    = ctl + CTL_BAR;
    unsigned* cnt    = ctl + CTL_CNT;
    unsigned* flag   = ctl + CTL_FLAG;
    unsigned* prefix = ctl + CTL_PREFIX;
    unsigned* krem   = ctl + CTL_KREM;
    float*    thr    = (float*)(ctl + CTL_THR);
    float*    ppsum  = (float*)(ctl + CTL_PPSUM);
    unsigned* ppcnt  = ctl + CTL_PPCNT;
    float*    opsum  = (float*)(ctl + CTL_OPSUM);
    unsigned* opcnt  = ctl + CTL_OPCNT;
    float*    bps    = (float*)(ctl + CTL_BPS);
    unsigned* bpc    = ctl + CTL_BPC;

    // Zero bar[2], cnt, flag (16 bytes) — stream-ordered, graph-capture-legal.
    hipMemsetAsync(ws + OFF_CTL + (size_t)CTL_BAR * 4, 0, 16, stream);

    fused_pass1<<<dim3(GRID_P1), 256, 0, stream>>>(mp, cp, bp, seg, bg, probA,
                                                   ppsum, ppcnt, bps, bpc,
                                                   cnt, flag, out);
    finish_all<<<dim3(256), 256, 0, stream>>>(probA, seg, ppsum, ppcnt, bps, bpc,
                                              hist, bar, prefix, krem, thr,
                                              opsum, opcnt, flag, out);
}

// Round 3
// 113.316 us; speedup vs baseline: 2.8398x; 1.3086x over previous
//
#include <hip/hip_runtime.h>

// Problem constants
#define NPX    2097152                // 4*512*1024 pixels per head
#define NPX4   (NPX/4)
#define CH_STR 8192                   // 64*128
#define IMG_STR 155648                // 19*8192

// Workspace: prob[2*NPX] floats at ws start, control region after.
#define OFF_CTL   (2ull*NPX*4)
// ctl layout in u32 units
#define CTL_HIST    0                   // [3 levels][2 heads][4096] = 24576 (slow path only)
#define CTL_CNT1    0                   // 64 buckets x 32-u32 stride (pass1 only; overlaps hist)
#define CTL_CNT2    2048                // level-2 completion counter (own cacheline)
#define CTL_BAR     24576               // u[2] software grid barrier (cnt, gen)
#define CTL_FLAG    24579               // u[1] magic flag (0 = not handled)
#define CTL_PREFIX  24580               // u[2]
#define CTL_KREM    24582               // u[2]
#define CTL_THR     24584               // f[2]
#define CTL_PPSUM   24586               // f[2*2048]
#define CTL_PPCNT   28682               // u[2*2048]
#define CTL_OPSUM   32778               // f[2*256]
#define CTL_OPCNT   33290               // u[2*256]
#define CTL_BPS     33802               // f[512*2]
#define CTL_BPC     34826               // u[512*2]

#define MAGIC_FAST 0x3A9C67E5u
#define GRID_P1    4608u               // 72 * 64: every bk&63 bucket gets exactly 72

// Device-coherent (cross-XCD) single-access ops: relaxed AGENT atomics compile
// to global_load/store with sc1 (write-through / L2-bypass) — NO L2 flush,
// unlike __threadfence() which emits buffer_wbl2/inv (the R1 250µs regression).
__device__ __forceinline__ void st_dev_f(float* p, float v) {
    __hip_atomic_store(p, v, __ATOMIC_RELAXED, __HIP_MEMORY_SCOPE_AGENT);
}
__device__ __forceinline__ void st_dev_u(unsigned* p, unsigned v) {
    __hip_atomic_store(p, v, __ATOMIC_RELAXED, __HIP_MEMORY_SCOPE_AGENT);
}
__device__ __forceinline__ float ld_dev_f(const float* p) {
    return __hip_atomic_load((float*)p, __ATOMIC_RELAXED, __HIP_MEMORY_SCOPE_AGENT);
}
__device__ __forceinline__ unsigned ld_dev_u(const unsigned* p) {
    return __hip_atomic_load((unsigned*)p, __ATOMIC_RELAXED, __HIP_MEMORY_SCOPE_AGENT);
}

// ---------------------------------------------------------------------------
// Pass 1: blocks [0,4096) = OHEM (one block per output row, XCD-swizzled);
// blocks [4096,4608) = boundary BCE. Hot math is the measured-best R6
// variant, bit-identical. Completion tracking is hierarchical (64 padded
// level-1 counters + 1 level-2) so same-address RMW serialization — the R2
// ~40µs tail — collapses to ~72 ops/line in parallel. The last-finishing
// block re-reads partials with sc1 loads in the EXACT FP order of
// finish_all's decide/combine, writes out[0] on the fast path, sets flag.
// ---------------------------------------------------------------------------
__global__ __launch_bounds__(256) void fused_pass1(
    const float* __restrict__ mp, const float* __restrict__ cp,
    const float* __restrict__ bp, const int* __restrict__ seg,
    const float* __restrict__ bg,
    float* __restrict__ probA, float* __restrict__ ppsum, unsigned* __restrict__ ppcnt,
    float* __restrict__ bps, unsigned* __restrict__ bpc,
    unsigned* __restrict__ cnt1, unsigned* __restrict__ cnt2,
    unsigned* __restrict__ flag,
    float* __restrict__ out)
{
    __shared__ float2 erow[19 * 128];          // 19.5 KB (reused as finisher scratch)
    __shared__ float rf[4]; __shared__ unsigned ru[4];
    __shared__ float rf2[4]; __shared__ unsigned ru2[4];
    __shared__ unsigned amLast;
    __shared__ float Pb[4], Nb[4]; __shared__ unsigned PCb[4], NCb[4];
    int bk = blockIdx.x;
    int tid = threadIdx.x;

    if (bk < 4096) {
        // XCD-locality swizzle: keep the 8 rows of each y-octave on one XCD
        // (same bk&7 => same XCD under round-robin dispatch). Bijection:
        // bk -> (x=bk&7, j=bk>>3) -> v = (j>>3)*64 + x*8 + (j&7).
        int x = bk & 7, j = bk >> 3;
        int v = ((j >> 3) << 6) | (x << 3) | (j & 7);
        int head = v >> 11;
        int task = v & 2047;                   // 2048 rows (4 samples * 512)
        int b = task >> 9;
        int y = task & 511;
        const float* pred = head ? cp : mp;

        float fy = (float)y * (63.0f / 511.0f);
        int y0 = min((int)fy, 63);
        int y1 = min(y0 + 1, 63);
        float wy = fy - (float)y0;

        const float* r0 = pred + (size_t)b * IMG_STR + y0 * 128;
        const float* r1 = pred + (size_t)b * IMG_STR + y1 * 128;
        for (int i = tid; i < 2432; i += 256) {      // 19*128
            int c = i >> 7, xx = i & 127;
            float v0 = r0[c * CH_STR + xx];
            float v1 = r1[c * CH_STR + xx];
            float e = fmaf(wy, v1 - v0, v0);
            erow[c * 128 + xx].x = e;
            if (xx > 0)    erow[c * 128 + xx - 1].y = e;
            if (xx == 127) erow[c * 128 + 127].y = e;   // pad; weight is 0 there
        }
        __syncthreads();

        int xb = tid << 2;
        int P = (b * 512 + y) * 1024 + xb;           // per-head pixel index
        int4 t4 = *(const int4*)(seg + P);
        int t[4] = {t4.x, t4.y, t4.z, t4.w};

        float fx0 = (float)xb * (127.0f / 1023.0f);
        int X = min((int)fx0, 126);                  // taps e[X], e[X+1], e[X+2]
        float wA[4], wB[4], wC[4];
#pragma unroll
        for (int dx = 0; dx < 4; ++dx) {
            float fx = (float)(xb + dx) * (127.0f / 1023.0f);
            int x0 = min((int)fx, 127);
            float wx = fx - (float)x0;
            bool sm = (x0 == X);
            wA[dx] = sm ? (1.0f - wx) : 0.0f;        // weight on e[X]   (eA.x)
            wB[dx] = sm ? wx : (1.0f - wx);          // weight on e[X+1] (eA.y)
            wC[dx] = sm ? 0.0f : wx;                 // weight on e[X+2] (eB.y)
        }

        float s[4] = {0.f, 0.f, 0.f, 0.f};
        for (int c = 0; c < 19; ++c) {
            float2 eA = erow[c * 128 + X];           // (e[X],   e[X+1])
            float2 eB = erow[c * 128 + X + 1];       // (e[X+1], e[X+2])
#pragma unroll
            for (int dx = 0; dx < 4; ++dx) {
                float l = fmaf(eA.x, wA[dx], fmaf(eA.y, wB[dx], eB.y * wC[dx]));
                s[dx] += __expf(l);
            }
        }

        float fs = 0.f; unsigned ic = 0;
        float pr[4];
#pragma unroll
        for (int dx = 0; dx < 4; ++dx) {
            bool valid = (t[dx] != 255);
            int tc = valid ? t[dx] : 0;
            float2 eA = erow[tc * 128 + X];
            float2 eB = erow[tc * 128 + X + 1];
            float lt = fmaf(eA.x, wA[dx], fmaf(eA.y, wB[dx], eB.y * wC[dx]));  // bit-identical
            float ls = __logf(s[dx]);
            float n  = ls - lt;                      // nll at target
            float p  = fminf(__expf(-n), 1.0f);
            pr[dx] = valid ? p : 1.0f;               // mask_prob (matches reference)
            if (valid && p <= 0.7f) { fs += n; ic++; }
        }
        *(float4*)(probA + (size_t)head * NPX + P) = make_float4(pr[0], pr[1], pr[2], pr[3]);

        for (int o = 32; o; o >>= 1) {
            fs += __shfl_down(fs, o, 64);
            ic += (unsigned)__shfl_down((int)ic, o, 64);
        }
        int wave = tid >> 6, lane = tid & 63;
        if (lane == 0) { rf[wave] = fs; ru[wave] = ic; }
        __syncthreads();
        if (tid == 0) {
            st_dev_f(&ppsum[head * 2048 + task], rf[0] + rf[1] + rf[2] + rf[3]);
            st_dev_u(&ppcnt[head * 2048 + task], ru[0] + ru[1] + ru[2] + ru[3]);
        }
    } else {
        // -------- boundary BCE --------
        int bb = bk - 4096;                   // [0,512)
        int b  = bb >> 7;                     // 128 blocks per sample
        int blk = bb & 127;
        float psum = 0.f, nsum = 0.f; unsigned pc = 0, nc = 0;

        for (int g = blk * 256 + tid; g < 131072; g += 128 * 256) {
            int P = g << 2;
            int y = P >> 10, xb = P & 1023;

            float fy = (float)y * (63.0f / 511.0f);
            int y0 = min((int)fy, 63);
            int y1 = min(y0 + 1, 63);
            float wy = fy - (float)y0;

            const float* r0 = bp + b * 8192 + y0 * 128;
            const float* r1 = bp + b * 8192 + y1 * 128;
            float fx0 = (float)xb * (127.0f / 1023.0f);
            int X  = min((int)fx0, 126);
            int X2 = min(X + 2, 127);
            float c0 = r0[X], c1 = r0[X + 1], c2 = r0[X2];
            float d0 = r1[X], d1 = r1[X + 1], d2 = r1[X2];
            float e0 = fmaf(wy, d0 - c0, c0);
            float e1 = fmaf(wy, d1 - c1, c1);
            float e2 = fmaf(wy, d2 - c2, c2);

            float4 t4 = *(const float4*)(bg + (size_t)b * 524288 + P);
            float tv[4] = {t4.x, t4.y, t4.z, t4.w};

#pragma unroll
            for (int dx = 0; dx < 4; ++dx) {
                float fx = (float)(xb + dx) * (127.0f / 1023.0f);
                int x0 = min((int)fx, 127);
                int x1 = min(x0 + 1, 127);
                float wx = fx - (float)x0;
                float a0 = (x0 == X)     ? e0 : e1;
                float a1 = (x1 == X + 1) ? e1 : e2;
                float p  = fmaf(wx, a1 - a0, a0);
                bool isp = (tv[dx] == 1.0f);
                bool isn = (tv[dx] == 0.0f);
                float q = isp ? p : 1.0f - p;
                float l = fmaxf(__logf(q), -100.0f);
                if (isp) { pc++; psum -= l; }
                if (isn) { nc++; nsum -= l; }
            }
        }
        for (int o = 32; o; o >>= 1) {
            psum += __shfl_down(psum, o, 64);
            nsum += __shfl_down(nsum, o, 64);
            pc   += (unsigned)__shfl_down((int)pc, o, 64);
            nc   += (unsigned)__shfl_down((int)nc, o, 64);
        }
        int wave = tid >> 6, lane = tid & 63;
        if (lane == 0) { rf[wave] = psum; rf2[wave] = nsum; ru[wave] = pc; ru2[wave] = nc; }
        __syncthreads();
        if (tid == 0) {
            st_dev_f(&bps[2 * bb],     rf[0] + rf[1] + rf[2] + rf[3]);
            st_dev_f(&bps[2 * bb + 1], rf2[0] + rf2[1] + rf2[2] + rf2[3]);
            st_dev_u(&bpc[2 * bb],     ru[0] + ru[1] + ru[2] + ru[3]);
            st_dev_u(&bpc[2 * bb + 1], ru2[0] + ru2[1] + ru2[2] + ru2[3]);
        }
    }

    // ---------------- last-block fused finisher (fast path only) ----------------
    // Hierarchical completion: 72 blocks per level-1 bucket (own cacheline),
    // bucket winners (lvl1 old==71) bump level-2; lvl2 old==63 => last block.
    // tid0's sc1 partial stores drained (vmcnt) BEFORE its lvl1 add; each add's
    // result is consumed before the next level => transitively all 4608 blocks'
    // partials are at the coherence point when lvl2 hits 64.
    __syncthreads();
    if (tid == 0) {
        asm volatile("s_waitcnt vmcnt(0)" ::: "memory");
        unsigned last = 0u;
        unsigned o1 = __hip_atomic_fetch_add(&cnt1[(bk & 63) << 5], 1u,
                                             __ATOMIC_RELAXED, __HIP_MEMORY_SCOPE_AGENT);
        if (o1 == 71u) {
            unsigned o2 = __hip_atomic_fetch_add(cnt2, 1u,
                                                 __ATOMIC_RELAXED, __HIP_MEMORY_SCOPE_AGENT);
            last = (o2 == 63u) ? 1u : 0u;
        }
        amLast = last;
    }
    __syncthreads();
    if (!amLast) return;

    // ---- decide (identical FP order to finish_all's redundant decide) ----
    float s0 = 0.f, s1 = 0.f; unsigned c0 = 0u, c1 = 0u;
    for (int i = tid; i < 2048; i += 256) {
        s0 += ld_dev_f(&ppsum[i]);        c0 += ld_dev_u(&ppcnt[i]);
        s1 += ld_dev_f(&ppsum[2048 + i]); c1 += ld_dev_u(&ppcnt[2048 + i]);
    }
    for (int o = 32; o; o >>= 1) {
        s0 += __shfl_down(s0, o, 64); s1 += __shfl_down(s1, o, 64);
        c0 += (unsigned)__shfl_down((int)c0, o, 64);
        c1 += (unsigned)__shfl_down((int)c1, o, 64);
    }
    int wv = tid >> 6, ln = tid & 63;
    if (ln == 0) { rf[wv] = s0; rf2[wv] = s1; ru[wv] = c0; ru2[wv] = c1; }
    __syncthreads();
    float S0 = rf[0] + rf[1] + rf[2] + rf[3];
    float S1 = rf2[0] + rf2[1] + rf2[2] + rf2[3];
    unsigned C0 = ru[0] + ru[1] + ru[2] + ru[3];
    unsigned C1 = ru2[0] + ru2[1] + ru2[2] + ru2[3];
    bool fast = (C0 >= 100000u) && (C1 >= 100000u);

    if (fast) {
        // boundary combine — same tree algorithm/order as combine_out
        float*    lf = (float*)erow;
        unsigned* lu = (unsigned*)erow + 256;
        for (int b = 0; b < 4; ++b) {
            float ps = 0.f, ns = 0.f; unsigned p_c = 0, n_c = 0;
            if (tid < 128) {
                int jj = b * 128 + tid;
                ps  = ld_dev_f(&bps[2 * jj]); ns  = ld_dev_f(&bps[2 * jj + 1]);
                p_c = ld_dev_u(&bpc[2 * jj]); n_c = ld_dev_u(&bpc[2 * jj + 1]);
            }
            lf[tid] = ps; lu[tid] = p_c; __syncthreads();
            for (int o = 128; o; o >>= 1) {
                if (tid < o) { lf[tid] += lf[tid + o]; lu[tid] += lu[tid + o]; }
                __syncthreads();
            }
            if (tid == 0) { Pb[b] = lf[0]; PCb[b] = lu[0]; }
            __syncthreads();
            lf[tid] = ns; lu[tid] = n_c; __syncthreads();
            for (int o = 128; o; o >>= 1) {
                if (tid < o) { lf[tid] += lf[tid + o]; lu[tid] += lu[tid + o]; }
                __syncthreads();
            }
            if (tid == 0) { Nb[b] = lf[0]; NCb[b] = lu[0]; }
            __syncthreads();
        }
        if (tid == 0) {
            float bt = 0.f;
            for (int b = 0; b < 4; ++b) {
                float pos = (float)PCb[b], neg = (float)NCb[b];
                float val = fmaxf(pos + neg, 1.f);
                bt += (neg / val) * Pb[b] + (pos / val) * Nb[b];
            }
            float hls = S0 / fmaxf((float)C0, 1.f) + S1 / fmaxf((float)C1, 1.f);
            out[0] = hls + bt / 2097152.0f;
            st_dev_u(flag, MAGIC_FAST);   // finish_all reads after kernel boundary
        }
    }
    // !fast: flag stays 0 (memset) -> finish_all runs its full original logic
}

// ---------------------------------------------------------------------------
// Software grid barrier (sense-reversing), agent scope. SLOW PATH ONLY.
// ---------------------------------------------------------------------------
__device__ __forceinline__ void gbar(unsigned* bar, int tid) {
    __syncthreads();
    if (tid == 0) {
        unsigned g = __hip_atomic_load(&bar[1], __ATOMIC_RELAXED, __HIP_MEMORY_SCOPE_AGENT);
        unsigned t = __hip_atomic_fetch_add(&bar[0], 1u, __ATOMIC_ACQ_REL, __HIP_MEMORY_SCOPE_AGENT);
        if (t == 255u) {
            __hip_atomic_store(&bar[0], 0u, __ATOMIC_RELAXED, __HIP_MEMORY_SCOPE_AGENT);
            __hip_atomic_store(&bar[1], g + 1u, __ATOMIC_RELEASE, __HIP_MEMORY_SCOPE_AGENT);
        } else {
            while (__hip_atomic_load(&bar[1], __ATOMIC_ACQUIRE, __HIP_MEMORY_SCOPE_AGENT) == g)
                __builtin_amdgcn_s_sleep(8);
        }
    }
    __syncthreads();
}

// Block 0: reduce per-sample boundary partials and write the final output.
__device__ void combine_out(int tid, float headLossSum,
                            const float* __restrict__ bps, const unsigned* __restrict__ bpc,
                            float* __restrict__ out)
{
    __shared__ float lf[256]; __shared__ unsigned lu[256];
    __shared__ float Pb[4], Nb[4]; __shared__ unsigned PCb[4], NCb[4];
    for (int b = 0; b < 4; ++b) {
        float ps = 0.f, ns = 0.f; unsigned p_c = 0, n_c = 0;
        if (tid < 128) {
            int j = b * 128 + tid;
            ps = bps[2 * j]; ns = bps[2 * j + 1];
            p_c = bpc[2 * j]; n_c = bpc[2 * j + 1];
        }
        lf[tid] = ps; lu[tid] = p_c; __syncthreads();
        for (int o = 128; o; o >>= 1) {
            if (tid < o) { lf[tid] += lf[tid + o]; lu[tid] += lu[tid + o]; }
            __syncthreads();
        }
        if (tid == 0) { Pb[b] = lf[0]; PCb[b] = lu[0]; }
        __syncthreads();
        lf[tid] = ns; lu[tid] = n_c; __syncthreads();
        for (int o = 128; o; o >>= 1) {
            if (tid < o) { lf[tid] += lf[tid + o]; lu[tid] += lu[tid + o]; }
            __syncthreads();
        }
        if (tid == 0) { Nb[b] = lf[0]; NCb[b] = lu[0]; }
        __syncthreads();
    }
    if (tid == 0) {
        float bt = 0.f;
        for (int b = 0; b < 4; ++b) {
            float pos = (float)PCb[b], neg = (float)NCb[b];
            float val = fmaxf(pos + neg, 1.f);
            bt += (neg / val) * Pb[b] + (pos / val) * Nb[b];
        }
        out[0] = headLossSum + bt / 2097152.0f;
    }
}

// ---------------------------------------------------------------------------
// Finisher (regular launch, 256 blocks). Early-exit when pass1's fused
// finisher already handled the fast path (magic flag). Any other flag value
// (0 from memset, since the fused finisher didn't take the fast path) falls
// through to the full original logic, which is self-sufficient.
// ---------------------------------------------------------------------------
__global__ __launch_bounds__(256) void finish_all(
    const float* __restrict__ probA, const int* __restrict__ seg,
    const float* __restrict__ ppsum, const unsigned* __restrict__ ppcnt,
    const float* __restrict__ bps, const unsigned* __restrict__ bpc,
    unsigned* __restrict__ hist, unsigned* __restrict__ bar,
    unsigned* __restrict__ prefix, unsigned* __restrict__ krem,
    float* __restrict__ thr,
    float* __restrict__ opsum, unsigned* __restrict__ opcnt,
    unsigned* __restrict__ flag,
    float* __restrict__ out)
{
    if (*flag == MAGIC_FAST)                  // kernel boundary => visible
        return;                               // fast path fully handled in pass1

    int tid = threadIdx.x, blk = blockIdx.x;
    int wave = tid >> 6, lane = tid & 63;

    // ---- redundant decide ----
    float s0 = 0.f, s1 = 0.f; unsigned c0 = 0u, c1 = 0u;
    for (int i = tid; i < 2048; i += 256) {
        s0 += ppsum[i];        c0 += ppcnt[i];
        s1 += ppsum[2048 + i]; c1 += ppcnt[2048 + i];
    }
    for (int o = 32; o; o >>= 1) {
        s0 += __shfl_down(s0, o, 64); s1 += __shfl_down(s1, o, 64);
        c0 += (unsigned)__shfl_down((int)c0, o, 64);
        c1 += (unsigned)__shfl_down((int)c1, o, 64);
    }
    __shared__ float ws0[4], ws1[4]; __shared__ unsigned wc0[4], wc1[4];
    if (lane == 0) { ws0[wave] = s0; ws1[wave] = s1; wc0[wave] = c0; wc1[wave] = c1; }
    __syncthreads();
    float S0 = ws0[0] + ws0[1] + ws0[2] + ws0[3];
    float S1 = ws1[0] + ws1[1] + ws1[2] + ws1[3];
    unsigned C0 = wc0[0] + wc0[1] + wc0[2] + wc0[3];
    unsigned C1 = wc1[0] + wc1[1] + wc1[2] + wc1[3];
    bool done0 = C0 >= 100000u, done1 = C1 >= 100000u;

    if (done0 && done1) {        // fast path fallback: thr = 0.7 exactly for both heads
        if (blk == 0)
            combine_out(tid, S0 / fmaxf((float)C0, 1.f) + S1 / fmaxf((float)C1, 1.f),
                        bps, bpc, out);
        return;
    }

    // ---------------- slow path: exact radix select over float bits ----------------
    __shared__ unsigned hsh[4096];
    __shared__ unsigned cpre[257];
    unsigned doneMask = (done0 ? 1u : 0u) | (done1 ? 2u : 0u);

    for (int i = blk * 256 + tid; i < 24576; i += 65536) hist[i] = 0u;
    gbar(bar, tid);

    for (int lvl = 0; lvl < 3; ++lvl) {
        unsigned* hl = hist + lvl * 8192;
        for (int h = 0; h < 2; ++h) {
            if (doneMask & (1u << h)) continue;
            unsigned pre = (lvl == 0) ? 0u : prefix[h];
            for (int i = tid; i < 4096; i += 256) hsh[i] = 0u;
            __syncthreads();
            const float4* prob = (const float4*)(probA + (size_t)h * NPX);
            for (int i = blk * 256 + tid; i < NPX4; i += 65536) {
                float4 p = prob[i];
                unsigned u[4] = {__float_as_uint(p.x), __float_as_uint(p.y),
                                 __float_as_uint(p.z), __float_as_uint(p.w)};
#pragma unroll
                for (int k = 0; k < 4; ++k) {
                    unsigned bv = u[k];
                    if (lvl == 0)      atomicAdd(&hsh[bv >> 18], 1u);
                    else if (lvl == 1) { if ((bv >> 18) == pre) atomicAdd(&hsh[(bv >> 6) & 0xFFFu], 1u); }
                    else               { if ((bv >> 6) == pre) atomicAdd(&hsh[bv & 63u], 1u); }
                }
            }
            __syncthreads();
            for (int i = tid; i < 4096; i += 256) {
                unsigned v = hsh[i];
                if (v) atomicAdd(&hl[h * 4096 + i], v);
            }
            __syncthreads();
        }
        gbar(bar, tid);
        if (blk == 0) {
            int bins = (lvl == 2) ? 64 : 4096;
            for (int h = 0; h < 2; ++h) {
                if (doneMask & (1u << h)) continue;
                const unsigned* hh = hl + h * 4096;
                int per = (bins + 255) >> 8;
                int base = tid * per;
                unsigned ssum = 0;
                for (int i = 0; i < per; ++i) { int idx = base + i; if (idx < bins) ssum += hh[idx]; }
                cpre[tid] = ssum; __syncthreads();
                if (tid == 0) {
                    unsigned acc = 0;
                    for (int i = 0; i < 256; ++i) { unsigned v = cpre[i]; cpre[i] = acc; acc += v; }
                    cpre[256] = acc;
                }
                __syncthreads();
                unsigned K = (lvl == 0) ? 100000u : krem[h];
                unsigned my = cpre[tid], nx = cpre[tid + 1];
                if (K > 0 && my < K && K <= nx) {
                    unsigned acc = my;
                    for (int i = 0; i < per; ++i) {
                        int idx = base + i;
                        unsigned c = (idx < bins) ? hh[idx] : 0u;
                        if (acc < K && K <= acc + c) {
                            if (lvl == 0)      { prefix[h] = (unsigned)idx; krem[h] = K - acc; }
                            else if (lvl == 1) { prefix[h] = (prefix[h] << 12) | (unsigned)idx; krem[h] = K - acc; }
                            else {
                                unsigned bitsv = (prefix[h] << 6) | (unsigned)idx;
                                thr[h] = fmaxf(0.7f, __uint_as_float(bitsv));
                            }
                            break;
                        }
                        acc += c;
                    }
                }
                __syncthreads();
            }
        }
        gbar(bar, tid);
    }

    // masked reduce with exact thr (nll recomputed as -log(prob))
    for (int h = 0; h < 2; ++h) {
        if (doneMask & (1u << h)) continue;
        float th = thr[h];
        const float4* prob = (const float4*)(probA + (size_t)h * NPX);
        const int4*   sg4  = (const int4*)seg;
        float fs = 0.f; unsigned ic = 0;
        for (int i = blk * 256 + tid; i < NPX4; i += 65536) {
            float4 p = prob[i]; int4 tt = sg4[i];
            if (tt.x != 255 && p.x <= th) { fs -= __logf(p.x); ic++; }
            if (tt.y != 255 && p.y <= th) { fs -= __logf(p.y); ic++; }
            if (tt.z != 255 && p.z <= th) { fs -= __logf(p.z); ic++; }
            if (tt.w != 255 && p.w <= th) { fs -= __logf(p.w); ic++; }
        }
        for (int o = 32; o; o >>= 1) {
            fs += __shfl_down(fs, o, 64);
            ic += (unsigned)__shfl_down((int)ic, o, 64);
        }
        __shared__ float wf[4]; __shared__ unsigned wu[4];
        if (lane == 0) { wf[wave] = fs; wu[wave] = ic; }
        __syncthreads();
        if (tid == 0) {
            opsum[h * 256 + blk] = wf[0] + wf[1] + wf[2] + wf[3];
            opcnt[h * 256 + blk] = wu[0] + wu[1] + wu[2] + wu[3];
        }
        __syncthreads();
    }
    gbar(bar, tid);
    if (blk == 0) {
        __shared__ float lf2[256]; __shared__ unsigned lu2[256];
        float hls = 0.f;
        for (int h = 0; h < 2; ++h) {
            float S; unsigned C;
            if (doneMask & (1u << h)) {
                S = h ? S1 : S0; C = h ? C1 : C0;
            } else {
                lf2[tid] = opsum[h * 256 + tid]; lu2[tid] = opcnt[h * 256 + tid];
                __syncthreads();
                for (int o = 128; o; o >>= 1) {
                    if (tid < o) { lf2[tid] += lf2[tid + o]; lu2[tid] += lu2[tid + o]; }
                    __syncthreads();
                }
                S = lf2[0]; C = lu2[0];
                __syncthreads();
            }
            hls += S / fmaxf((float)C, 1.f);
        }
        combine_out(tid, hls, bps, bpc, out);
    }
}

extern "C" void kernel_launch(void* const* d_in, const int* in_sizes, int n_in,
                              void* d_out, int out_size, void* d_ws, size_t ws_size,
                              hipStream_t stream)
{
    const float* mp  = (const float*)d_in[0];
    const float* cp  = (const float*)d_in[1];
    const float* bp  = (const float*)d_in[2];
    const int*   seg = (const int*)d_in[3];
    const float* bg  = (const float*)d_in[4];
    float* out = (float*)d_out;

    char* ws = (char*)d_ws;
    float* probA = (float*)ws;
    unsigned* ctl    = (unsigned*)(ws + OFF_CTL);
    unsigned* hist   = ctl + CTL_HIST;
    unsigned* cnt1   = ctl + CTL_CNT1;
    unsigned* cnt2   = ctl + CTL_CNT2;
    unsigned* bar    = ctl + CTL_BAR;
    unsigned* flag   = ctl + CTL_FLAG;
    unsigned* prefix = ctl + CTL_PREFIX;
    unsigned* krem   = ctl + CTL_KREM;
    float*    thr    = (float*)(ctl + CTL_THR);
    float*    ppsum  = (float*)(ctl + CTL_PPSUM);
    unsigned* ppcnt  = ctl + CTL_PPCNT;
    float*    opsum  = (float*)(ctl + CTL_OPSUM);
    unsigned* opcnt  = ctl + CTL_OPCNT;
    float*    bps    = (float*)(ctl + CTL_BPS);
    unsigned* bpc    = ctl + CTL_BPC;

    // Zero hist-region counters (cnt1/cnt2), bar, flag in ONE stream-ordered
    // memset: ctl u32 [0, 24580) = 98320 bytes (hist is re-zeroed by the slow
    // path itself; zeroing it here is harmless).
    hipMemsetAsync(ws + OFF_CTL, 0, 24580ull * 4, stream);

    fused_pass1<<<dim3(GRID_P1), 256, 0, stream>>>(mp, cp, bp, seg, bg, probA,
                                                   ppsum, ppcnt, bps, bpc,
                                                   cnt1, cnt2, flag, out);
    finish_all<<<dim3(256), 256, 0, stream>>>(probA, seg, ppsum, ppcnt, bps, bpc,
                                              hist, bar, prefix, krem, thr,
                                              opsum, opcnt, flag, out);
}

// Round 4
// 113.051 us; speedup vs baseline: 2.8465x; 1.0023x over previous
//
#include <hip/hip_runtime.h>

// Problem constants
#define NPX    2097152                // 4*512*1024 pixels per head
#define NPX4   (NPX/4)
#define CH_STR 8192                   // 64*128
#define IMG_STR 155648                // 19*8192

// Workspace: prob[2*NPX] floats at ws start, control region after.
#define OFF_CTL   (2ull*NPX*4)
// ctl layout in u32 units
#define CTL_HIST    0                   // [3 levels][2 heads][4096] = 24576 (slow path only)
#define CTL_CNT1    0                   // 64 buckets x 32-u32 stride (pass1 only; overlaps hist)
#define CTL_CNT2    2048                // level-2 completion counter (own cacheline)
#define CTL_BAR     24576               // u[2] software grid barrier (cnt, gen)
#define CTL_FLAG    24579               // u[1] magic flag (0 = not handled)
#define CTL_PREFIX  24580               // u[2]
#define CTL_KREM    24582               // u[2]
#define CTL_THR     24584               // f[2]
#define CTL_PPSUM   24586               // f[2*2048]
#define CTL_PPCNT   28682               // u[2*2048]
#define CTL_OPSUM   32778               // f[2*256]
#define CTL_OPCNT   33290               // u[2*256]
#define CTL_BPS     33802               // f[512*2]
#define CTL_BPC     34826               // u[512*2]

#define MAGIC_FAST 0x3A9C67E5u
#define GRID_P1    1536u               // 1024 OHEM (4-row groups) + 512 BCE = 24 * 64

// Device-coherent (cross-XCD) single-access ops: relaxed AGENT atomics compile
// to global_load/store with sc1 (write-through / L2-bypass) — NO L2 flush,
// unlike __threadfence() which emits buffer_wbl2/inv (the R1 250µs regression).
__device__ __forceinline__ void st_dev_f(float* p, float v) {
    __hip_atomic_store(p, v, __ATOMIC_RELAXED, __HIP_MEMORY_SCOPE_AGENT);
}
__device__ __forceinline__ void st_dev_u(unsigned* p, unsigned v) {
    __hip_atomic_store(p, v, __ATOMIC_RELAXED, __HIP_MEMORY_SCOPE_AGENT);
}
__device__ __forceinline__ float ld_dev_f(const float* p) {
    return __hip_atomic_load((float*)p, __ATOMIC_RELAXED, __HIP_MEMORY_SCOPE_AGENT);
}
__device__ __forceinline__ unsigned ld_dev_u(const unsigned* p) {
    return __hip_atomic_load((unsigned*)p, __ATOMIC_RELAXED, __HIP_MEMORY_SCOPE_AGENT);
}

// ---------------------------------------------------------------------------
// Pass 1: blocks [0,1024) = OHEM, one block per 4-row output group. The 4
// rows of a group span <=2 distinct y0, so 3 raw input rows (clamped at 63)
// cover the group; they are staged ONCE into registers as float4s. Per output
// row, erow is rebuilt in LDS with the bit-identical fmaf(wy, v1-v0, v0) and
// written as 2x ds_write_b128 per slot (the (e[x],e[x+1]) float2-pair layout
// is preserved exactly; neighbor element via shfl; lane tid&31==31 is always
// a channel boundary so no cross-wave shuffle exists). The px loop / probA /
// partial reductions are verbatim from the measured-best R6 variant.
// Blocks [1024,1536) = boundary BCE (unchanged). Hierarchical completion:
// 24 blocks per level-1 bucket, 64 buckets -> level-2; last block runs the
// fast-path decide+combine (exact finish_all FP order) and sets the flag.
// ---------------------------------------------------------------------------
__global__ __launch_bounds__(256, 5) void fused_pass1(
    const float* __restrict__ mp, const float* __restrict__ cp,
    const float* __restrict__ bp, const int* __restrict__ seg,
    const float* __restrict__ bg,
    float* __restrict__ probA, float* __restrict__ ppsum, unsigned* __restrict__ ppcnt,
    float* __restrict__ bps, unsigned* __restrict__ bpc,
    unsigned* __restrict__ cnt1, unsigned* __restrict__ cnt2,
    unsigned* __restrict__ flag,
    float* __restrict__ out)
{
    __shared__ float2 erow[19 * 128];          // 19.5 KB (reused as finisher scratch)
    __shared__ float rf[4]; __shared__ unsigned ru[4];
    __shared__ float rf2[4]; __shared__ unsigned ru2[4];
    __shared__ unsigned amLast;
    __shared__ float Pb[4], Nb[4]; __shared__ unsigned PCb[4], NCb[4];
    int bk = blockIdx.x;
    int tid = threadIdx.x;

    if (bk < 1024) {
        // Chunked XCD swizzle: XCD (bk&7) gets 128 consecutive groups = one
        // (head,b) image slice (1.2 MB -> L2-resident on that XCD).
        int v = ((bk & 7) << 7) | (bk >> 3);
        int head = v >> 9;
        int b    = (v >> 7) & 3;
        int k    = v & 127;                    // 4-row group: rows 4k..4k+3
        const float* pred = head ? cp : mp;

        // 3 raw input rows cover the group (window width < 1 in fy).
        int y0g = min((int)((float)(4 * k) * (63.0f / 511.0f)), 63);
        int row0 = y0g, row1 = min(y0g + 1, 63), row2 = min(y0g + 2, 63);

        // Register-stage the 3 rows: 608 float4 slots each, 3 rounds of 256.
        float4 rv[3][3];
#pragma unroll
        for (int r = 0; r < 3; ++r) {
            int ry = (r == 0) ? row0 : ((r == 1) ? row1 : row2);
            const float* rp = pred + (size_t)b * IMG_STR + ry * 128;
#pragma unroll
            for (int sr = 0; sr < 3; ++sr) {
                int s = tid + (sr << 8);
                if (s < 608) {
                    int c = s >> 5, x4 = (s & 31) << 2;
                    rv[r][sr] = *(const float4*)(rp + c * CH_STR + x4);
                } else {
                    rv[r][sr] = make_float4(0.f, 0.f, 0.f, 0.f);
                }
            }
        }

        // Per-thread horizontal taps/weights — invariant across the 4 rows.
        int xb = tid << 2;
        float fx0 = (float)xb * (127.0f / 1023.0f);
        int X = min((int)fx0, 126);                  // taps e[X], e[X+1], e[X+2]
        float wA[4], wB[4], wC[4];
#pragma unroll
        for (int dx = 0; dx < 4; ++dx) {
            float fx = (float)(xb + dx) * (127.0f / 1023.0f);
            int x0 = min((int)fx, 127);
            float wx = fx - (float)x0;
            bool sm = (x0 == X);
            wA[dx] = sm ? (1.0f - wx) : 0.0f;        // weight on e[X]   (eA.x)
            wB[dx] = sm ? wx : (1.0f - wx);          // weight on e[X+1] (eA.y)
            wC[dx] = sm ? 0.0f : wx;                 // weight on e[X+2] (eB.y)
        }

#pragma unroll 1
        for (int d = 0; d < 4; ++d) {
            int y = (k << 2) + d;
            int task = (b << 9) + y;                 // b*512 + y
            float fy = (float)y * (63.0f / 511.0f);
            int y0 = min((int)fy, 63);
            float wy = fy - (float)y0;
            int j = y0 - y0g;                        // 0 or 1, block-uniform

            // Prefetch seg early — latency hides under erow build + barrier.
            int P = task * 1024 + xb;                // per-head pixel index
            int4 t4 = *(const int4*)(seg + P);
            int t[4] = {t4.x, t4.y, t4.z, t4.w};

            // Build erow for this row from registers (bit-identical e values).
#pragma unroll
            for (int sr = 0; sr < 3; ++sr) {
                int s = tid + (sr << 8);
                float4 cu = (j == 0) ? rv[0][sr] : rv[1][sr];
                float4 nx = (j == 0) ? rv[1][sr] : rv[2][sr];
                float e0 = fmaf(wy, nx.x - cu.x, cu.x);
                float e1 = fmaf(wy, nx.y - cu.y, cu.y);
                float e2 = fmaf(wy, nx.z - cu.z, cu.z);
                float e3 = fmaf(wy, nx.w - cu.w, cu.w);
                float en = __shfl_down(e0, 1, 64);   // next slot's e0 (same wave)
                if (s < 608) {
                    int c = s >> 5, x4 = (s & 31) << 2;
                    float last = ((s & 31) == 31) ? e3 : en;  // channel edge pad
                    float4 w0 = make_float4(e0, e1, e1, e2);
                    float4 w1 = make_float4(e2, e3, e3, last);
                    *(float4*)(&erow[c * 128 + x4])     = w0;
                    *(float4*)(&erow[c * 128 + x4 + 2]) = w1;
                }
            }
            __syncthreads();

            // ---- px loop: verbatim hot math ----
            float acc[4] = {0.f, 0.f, 0.f, 0.f};
            for (int c = 0; c < 19; ++c) {
                float2 eA = erow[c * 128 + X];           // (e[X],   e[X+1])
                float2 eB = erow[c * 128 + X + 1];       // (e[X+1], e[X+2])
#pragma unroll
                for (int dx = 0; dx < 4; ++dx) {
                    float l = fmaf(eA.x, wA[dx], fmaf(eA.y, wB[dx], eB.y * wC[dx]));
                    acc[dx] += __expf(l);
                }
            }

            float fs = 0.f; unsigned ic = 0;
            float pr[4];
#pragma unroll
            for (int dx = 0; dx < 4; ++dx) {
                bool valid = (t[dx] != 255);
                int tc = valid ? t[dx] : 0;
                float2 eA = erow[tc * 128 + X];
                float2 eB = erow[tc * 128 + X + 1];
                float lt = fmaf(eA.x, wA[dx], fmaf(eA.y, wB[dx], eB.y * wC[dx]));  // bit-identical
                float ls = __logf(acc[dx]);
                float n  = ls - lt;                      // nll at target
                float p  = fminf(__expf(-n), 1.0f);
                pr[dx] = valid ? p : 1.0f;               // mask_prob (matches reference)
                if (valid && p <= 0.7f) { fs += n; ic++; }
            }
            *(float4*)(probA + (size_t)head * NPX + P) = make_float4(pr[0], pr[1], pr[2], pr[3]);

            for (int o = 32; o; o >>= 1) {
                fs += __shfl_down(fs, o, 64);
                ic += (unsigned)__shfl_down((int)ic, o, 64);
            }
            int wave = tid >> 6, lane = tid & 63;
            if (lane == 0) { rf[wave] = fs; ru[wave] = ic; }
            __syncthreads();
            if (tid == 0) {
                st_dev_f(&ppsum[head * 2048 + task], rf[0] + rf[1] + rf[2] + rf[3]);
                st_dev_u(&ppcnt[head * 2048 + task], ru[0] + ru[1] + ru[2] + ru[3]);
            }
            // No extra barrier needed: every thread passed the rf-sync above
            // before the next iteration's erow writes; tid0's rf reads are
            // ordered before lane0's next rf writes by the erow barrier.
        }
    } else {
        // -------- boundary BCE --------
        int bb = bk - 1024;                   // [0,512)
        int b  = bb >> 7;                     // 128 blocks per sample
        int blk = bb & 127;
        float psum = 0.f, nsum = 0.f; unsigned pc = 0, nc = 0;

        for (int g = blk * 256 + tid; g < 131072; g += 128 * 256) {
            int P = g << 2;
            int y = P >> 10, xb = P & 1023;

            float fy = (float)y * (63.0f / 511.0f);
            int y0 = min((int)fy, 63);
            int y1 = min(y0 + 1, 63);
            float wy = fy - (float)y0;

            const float* r0 = bp + b * 8192 + y0 * 128;
            const float* r1 = bp + b * 8192 + y1 * 128;
            float fx0 = (float)xb * (127.0f / 1023.0f);
            int X  = min((int)fx0, 126);
            int X2 = min(X + 2, 127);
            float c0 = r0[X], c1 = r0[X + 1], c2 = r0[X2];
            float d0 = r1[X], d1 = r1[X + 1], d2 = r1[X2];
            float e0 = fmaf(wy, d0 - c0, c0);
            float e1 = fmaf(wy, d1 - c1, c1);
            float e2 = fmaf(wy, d2 - c2, c2);

            float4 t4 = *(const float4*)(bg + (size_t)b * 524288 + P);
            float tv[4] = {t4.x, t4.y, t4.z, t4.w};

#pragma unroll
            for (int dx = 0; dx < 4; ++dx) {
                float fx = (float)(xb + dx) * (127.0f / 1023.0f);
                int x0 = min((int)fx, 127);
                int x1 = min(x0 + 1, 127);
                float wx = fx - (float)x0;
                float a0 = (x0 == X)     ? e0 : e1;
                float a1 = (x1 == X + 1) ? e1 : e2;
                float p  = fmaf(wx, a1 - a0, a0);
                bool isp = (tv[dx] == 1.0f);
                bool isn = (tv[dx] == 0.0f);
                float q = isp ? p : 1.0f - p;
                float l = fmaxf(__logf(q), -100.0f);
                if (isp) { pc++; psum -= l; }
                if (isn) { nc++; nsum -= l; }
            }
        }
        for (int o = 32; o; o >>= 1) {
            psum += __shfl_down(psum, o, 64);
            nsum += __shfl_down(nsum, o, 64);
            pc   += (unsigned)__shfl_down((int)pc, o, 64);
            nc   += (unsigned)__shfl_down((int)nc, o, 64);
        }
        int wave = tid >> 6, lane = tid & 63;
        if (lane == 0) { rf[wave] = psum; rf2[wave] = nsum; ru[wave] = pc; ru2[wave] = nc; }
        __syncthreads();
        if (tid == 0) {
            st_dev_f(&bps[2 * bb],     rf[0] + rf[1] + rf[2] + rf[3]);
            st_dev_f(&bps[2 * bb + 1], rf2[0] + rf2[1] + rf2[2] + rf2[3]);
            st_dev_u(&bpc[2 * bb],     ru[0] + ru[1] + ru[2] + ru[3]);
            st_dev_u(&bpc[2 * bb + 1], ru2[0] + ru2[1] + ru2[2] + ru2[3]);
        }
    }

    // ---------------- last-block fused finisher (fast path only) ----------------
    // Hierarchical completion: 24 blocks per level-1 bucket (own cacheline),
    // bucket winners (lvl1 old==23) bump level-2; lvl2 old==63 => last block.
    __syncthreads();
    if (tid == 0) {
        asm volatile("s_waitcnt vmcnt(0)" ::: "memory");
        unsigned last = 0u;
        unsigned o1 = __hip_atomic_fetch_add(&cnt1[(bk & 63) << 5], 1u,
                                             __ATOMIC_RELAXED, __HIP_MEMORY_SCOPE_AGENT);
        if (o1 == 23u) {
            unsigned o2 = __hip_atomic_fetch_add(cnt2, 1u,
                                                 __ATOMIC_RELAXED, __HIP_MEMORY_SCOPE_AGENT);
            last = (o2 == 63u) ? 1u : 0u;
        }
        amLast = last;
    }
    __syncthreads();
    if (!amLast) return;

    // ---- decide (identical FP order to finish_all's redundant decide) ----
    float s0 = 0.f, s1 = 0.f; unsigned c0 = 0u, c1 = 0u;
    for (int i = tid; i < 2048; i += 256) {
        s0 += ld_dev_f(&ppsum[i]);        c0 += ld_dev_u(&ppcnt[i]);
        s1 += ld_dev_f(&ppsum[2048 + i]); c1 += ld_dev_u(&ppcnt[2048 + i]);
    }
    for (int o = 32; o; o >>= 1) {
        s0 += __shfl_down(s0, o, 64); s1 += __shfl_down(s1, o, 64);
        c0 += (unsigned)__shfl_down((int)c0, o, 64);
        c1 += (unsigned)__shfl_down((int)c1, o, 64);
    }
    int wv = tid >> 6, ln = tid & 63;
    if (ln == 0) { rf[wv] = s0; rf2[wv] = s1; ru[wv] = c0; ru2[wv] = c1; }
    __syncthreads();
    float S0 = rf[0] + rf[1] + rf[2] + rf[3];
    float S1 = rf2[0] + rf2[1] + rf2[2] + rf2[3];
    unsigned C0 = ru[0] + ru[1] + ru[2] + ru[3];
    unsigned C1 = ru2[0] + ru2[1] + ru2[2] + ru2[3];
    bool fast = (C0 >= 100000u) && (C1 >= 100000u);

    if (fast) {
        // boundary combine — same tree algorithm/order as combine_out
        float*    lf = (float*)erow;
        unsigned* lu = (unsigned*)erow + 256;
        for (int b = 0; b < 4; ++b) {
            float ps = 0.f, ns = 0.f; unsigned p_c = 0, n_c = 0;
            if (tid < 128) {
                int jj = b * 128 + tid;
                ps  = ld_dev_f(&bps[2 * jj]); ns  = ld_dev_f(&bps[2 * jj + 1]);
                p_c = ld_dev_u(&bpc[2 * jj]); n_c = ld_dev_u(&bpc[2 * jj + 1]);
            }
            lf[tid] = ps; lu[tid] = p_c; __syncthreads();
            for (int o = 128; o; o >>= 1) {
                if (tid < o) { lf[tid] += lf[tid + o]; lu[tid] += lu[tid + o]; }
                __syncthreads();
            }
            if (tid == 0) { Pb[b] = lf[0]; PCb[b] = lu[0]; }
            __syncthreads();
            lf[tid] = ns; lu[tid] = n_c; __syncthreads();
            for (int o = 128; o; o >>= 1) {
                if (tid < o) { lf[tid] += lf[tid + o]; lu[tid] += lu[tid + o]; }
                __syncthreads();
            }
            if (tid == 0) { Nb[b] = lf[0]; NCb[b] = lu[0]; }
            __syncthreads();
        }
        if (tid == 0) {
            float bt = 0.f;
            for (int b = 0; b < 4; ++b) {
                float pos = (float)PCb[b], neg = (float)NCb[b];
                float val = fmaxf(pos + neg, 1.f);
                bt += (neg / val) * Pb[b] + (pos / val) * Nb[b];
            }
            float hls = S0 / fmaxf((float)C0, 1.f) + S1 / fmaxf((float)C1, 1.f);
            out[0] = hls + bt / 2097152.0f;
            st_dev_u(flag, MAGIC_FAST);   // finish_all reads after kernel boundary
        }
    }
    // !fast: flag stays 0 (memset) -> finish_all runs its full original logic
}

// ---------------------------------------------------------------------------
// Software grid barrier (sense-reversing), agent scope. SLOW PATH ONLY.
// ---------------------------------------------------------------------------
__device__ __forceinline__ void gbar(unsigned* bar, int tid) {
    __syncthreads();
    if (tid == 0) {
        unsigned g = __hip_atomic_load(&bar[1], __ATOMIC_RELAXED, __HIP_MEMORY_SCOPE_AGENT);
        unsigned t = __hip_atomic_fetch_add(&bar[0], 1u, __ATOMIC_ACQ_REL, __HIP_MEMORY_SCOPE_AGENT);
        if (t == 255u) {
            __hip_atomic_store(&bar[0], 0u, __ATOMIC_RELAXED, __HIP_MEMORY_SCOPE_AGENT);
            __hip_atomic_store(&bar[1], g + 1u, __ATOMIC_RELEASE, __HIP_MEMORY_SCOPE_AGENT);
        } else {
            while (__hip_atomic_load(&bar[1], __ATOMIC_ACQUIRE, __HIP_MEMORY_SCOPE_AGENT) == g)
                __builtin_amdgcn_s_sleep(8);
        }
    }
    __syncthreads();
}

// Block 0: reduce per-sample boundary partials and write the final output.
__device__ void combine_out(int tid, float headLossSum,
                            const float* __restrict__ bps, const unsigned* __restrict__ bpc,
                            float* __restrict__ out)
{
    __shared__ float lf[256]; __shared__ unsigned lu[256];
    __shared__ float Pb[4], Nb[4]; __shared__ unsigned PCb[4], NCb[4];
    for (int b = 0; b < 4; ++b) {
        float ps = 0.f, ns = 0.f; unsigned p_c = 0, n_c = 0;
        if (tid < 128) {
            int j = b * 128 + tid;
            ps = bps[2 * j]; ns = bps[2 * j + 1];
            p_c = bpc[2 * j]; n_c = bpc[2 * j + 1];
        }
        lf[tid] = ps; lu[tid] = p_c; __syncthreads();
        for (int o = 128; o; o >>= 1) {
            if (tid < o) { lf[tid] += lf[tid + o]; lu[tid] += lu[tid + o]; }
            __syncthreads();
        }
        if (tid == 0) { Pb[b] = lf[0]; PCb[b] = lu[0]; }
        __syncthreads();
        lf[tid] = ns; lu[tid] = n_c; __syncthreads();
        for (int o = 128; o; o >>= 1) {
            if (tid < o) { lf[tid] += lf[tid + o]; lu[tid] += lu[tid + o]; }
            __syncthreads();
        }
        if (tid == 0) { Nb[b] = lf[0]; NCb[b] = lu[0]; }
        __syncthreads();
    }
    if (tid == 0) {
        float bt = 0.f;
        for (int b = 0; b < 4; ++b) {
            float pos = (float)PCb[b], neg = (float)NCb[b];
            float val = fmaxf(pos + neg, 1.f);
            bt += (neg / val) * Pb[b] + (pos / val) * Nb[b];
        }
        out[0] = headLossSum + bt / 2097152.0f;
    }
}

// ---------------------------------------------------------------------------
// Finisher (regular launch, 256 blocks). Early-exit when pass1's fused
// finisher already handled the fast path (magic flag). Any other flag value
// (0 from memset, since the fused finisher didn't take the fast path) falls
// through to the full original logic, which is self-sufficient.
// ---------------------------------------------------------------------------
__global__ __launch_bounds__(256) void finish_all(
    const float* __restrict__ probA, const int* __restrict__ seg,
    const float* __restrict__ ppsum, const unsigned* __restrict__ ppcnt,
    const float* __restrict__ bps, const unsigned* __restrict__ bpc,
    unsigned* __restrict__ hist, unsigned* __restrict__ bar,
    unsigned* __restrict__ prefix, unsigned* __restrict__ krem,
    float* __restrict__ thr,
    float* __restrict__ opsum, unsigned* __restrict__ opcnt,
    unsigned* __restrict__ flag,
    float* __restrict__ out)
{
    if (*flag == MAGIC_FAST)                  // kernel boundary => visible
        return;                               // fast path fully handled in pass1

    int tid = threadIdx.x, blk = blockIdx.x;
    int wave = tid >> 6, lane = tid & 63;

    // ---- redundant decide ----
    float s0 = 0.f, s1 = 0.f; unsigned c0 = 0u, c1 = 0u;
    for (int i = tid; i < 2048; i += 256) {
        s0 += ppsum[i];        c0 += ppcnt[i];
        s1 += ppsum[2048 + i]; c1 += ppcnt[2048 + i];
    }
    for (int o = 32; o; o >>= 1) {
        s0 += __shfl_down(s0, o, 64); s1 += __shfl_down(s1, o, 64);
        c0 += (unsigned)__shfl_down((int)c0, o, 64);
        c1 += (unsigned)__shfl_down((int)c1, o, 64);
    }
    __shared__ float ws0[4], ws1[4]; __shared__ unsigned wc0[4], wc1[4];
    if (lane == 0) { ws0[wave] = s0; ws1[wave] = s1; wc0[wave] = c0; wc1[wave] = c1; }
    __syncthreads();
    float S0 = ws0[0] + ws0[1] + ws0[2] + ws0[3];
    float S1 = ws1[0] + ws1[1] + ws1[2] + ws1[3];
    unsigned C0 = wc0[0] + wc0[1] + wc0[2] + wc0[3];
    unsigned C1 = wc1[0] + wc1[1] + wc1[2] + wc1[3];
    bool done0 = C0 >= 100000u, done1 = C1 >= 100000u;

    if (done0 && done1) {        // fast path fallback: thr = 0.7 exactly for both heads
        if (blk == 0)
            combine_out(tid, S0 / fmaxf((float)C0, 1.f) + S1 / fmaxf((float)C1, 1.f),
                        bps, bpc, out);
        return;
    }

    // ---------------- slow path: exact radix select over float bits ----------------
    __shared__ unsigned hsh[4096];
    __shared__ unsigned cpre[257];
    unsigned doneMask = (done0 ? 1u : 0u) | (done1 ? 2u : 0u);

    for (int i = blk * 256 + tid; i < 24576; i += 65536) hist[i] = 0u;
    gbar(bar, tid);

    for (int lvl = 0; lvl < 3; ++lvl) {
        unsigned* hl = hist + lvl * 8192;
        for (int h = 0; h < 2; ++h) {
            if (doneMask & (1u << h)) continue;
            unsigned pre = (lvl == 0) ? 0u : prefix[h];
            for (int i = tid; i < 4096; i += 256) hsh[i] = 0u;
            __syncthreads();
            const float4* prob = (const float4*)(probA + (size_t)h * NPX);
            for (int i = blk * 256 + tid; i < NPX4; i += 65536) {
                float4 p = prob[i];
                unsigned u[4] = {__float_as_uint(p.x), __float_as_uint(p.y),
                                 __float_as_uint(p.z), __float_as_uint(p.w)};
#pragma unroll
                for (int kk = 0; kk < 4; ++kk) {
                    unsigned bv = u[kk];
                    if (lvl == 0)      atomicAdd(&hsh[bv >> 18], 1u);
                    else if (lvl == 1) { if ((bv >> 18) == pre) atomicAdd(&hsh[(bv >> 6) & 0xFFFu], 1u); }
                    else               { if ((bv >> 6) == pre) atomicAdd(&hsh[bv & 63u], 1u); }
                }
            }
            __syncthreads();
            for (int i = tid; i < 4096; i += 256) {
                unsigned v = hsh[i];
                if (v) atomicAdd(&hl[h * 4096 + i], v);
            }
            __syncthreads();
        }
        gbar(bar, tid);
        if (blk == 0) {
            int bins = (lvl == 2) ? 64 : 4096;
            for (int h = 0; h < 2; ++h) {
                if (doneMask & (1u << h)) continue;
                const unsigned* hh = hl + h * 4096;
                int per = (bins + 255) >> 8;
                int base = tid * per;
                unsigned ssum = 0;
                for (int i = 0; i < per; ++i) { int idx = base + i; if (idx < bins) ssum += hh[idx]; }
                cpre[tid] = ssum; __syncthreads();
                if (tid == 0) {
                    unsigned acc = 0;
                    for (int i = 0; i < 256; ++i) { unsigned v = cpre[i]; cpre[i] = acc; acc += v; }
                    cpre[256] = acc;
                }
                __syncthreads();
                unsigned K = (lvl == 0) ? 100000u : krem[h];
                unsigned my = cpre[tid], nx = cpre[tid + 1];
                if (K > 0 && my < K && K <= nx) {
                    unsigned acc = my;
                    for (int i = 0; i < per; ++i) {
                        int idx = base + i;
                        unsigned c = (idx < bins) ? hh[idx] : 0u;
                        if (acc < K && K <= acc + c) {
                            if (lvl == 0)      { prefix[h] = (unsigned)idx; krem[h] = K - acc; }
                            else if (lvl == 1) { prefix[h] = (prefix[h] << 12) | (unsigned)idx; krem[h] = K - acc; }
                            else {
                                unsigned bitsv = (prefix[h] << 6) | (unsigned)idx;
                                thr[h] = fmaxf(0.7f, __uint_as_float(bitsv));
                            }
                            break;
                        }
                        acc += c;
                    }
                }
                __syncthreads();
            }
        }
        gbar(bar, tid);
    }

    // masked reduce with exact thr (nll recomputed as -log(prob))
    for (int h = 0; h < 2; ++h) {
        if (doneMask & (1u << h)) continue;
        float th = thr[h];
        const float4* prob = (const float4*)(probA + (size_t)h * NPX);
        const int4*   sg4  = (const int4*)seg;
        float fs = 0.f; unsigned ic = 0;
        for (int i = blk * 256 + tid; i < NPX4; i += 65536) {
            float4 p = prob[i]; int4 tt = sg4[i];
            if (tt.x != 255 && p.x <= th) { fs -= __logf(p.x); ic++; }
            if (tt.y != 255 && p.y <= th) { fs -= __logf(p.y); ic++; }
            if (tt.z != 255 && p.z <= th) { fs -= __logf(p.z); ic++; }
            if (tt.w != 255 && p.w <= th) { fs -= __logf(p.w); ic++; }
        }
        for (int o = 32; o; o >>= 1) {
            fs += __shfl_down(fs, o, 64);
            ic += (unsigned)__shfl_down((int)ic, o, 64);
        }
        __shared__ float wf[4]; __shared__ unsigned wu[4];
        if (lane == 0) { wf[wave] = fs; wu[wave] = ic; }
        __syncthreads();
        if (tid == 0) {
            opsum[h * 256 + blk] = wf[0] + wf[1] + wf[2] + wf[3];
            opcnt[h * 256 + blk] = wu[0] + wu[1] + wu[2] + wu[3];
        }
        __syncthreads();
    }
    gbar(bar, tid);
    if (blk == 0) {
        __shared__ float lf2[256]; __shared__ unsigned lu2[256];
        float hls = 0.f;
        for (int h = 0; h < 2; ++h) {
            float S; unsigned C;
            if (doneMask & (1u << h)) {
                S = h ? S1 : S0; C = h ? C1 : C0;
            } else {
                lf2[tid] = opsum[h * 256 + tid]; lu2[tid] = opcnt[h * 256 + tid];
                __syncthreads();
                for (int o = 128; o; o >>= 1) {
                    if (tid < o) { lf2[tid] += lf2[tid + o]; lu2[tid] += lu2[tid + o]; }
                    __syncthreads();
                }
                S = lf2[0]; C = lu2[0];
                __syncthreads();
            }
            hls += S / fmaxf((float)C, 1.f);
        }
        combine_out(tid, hls, bps, bpc, out);
    }
}

extern "C" void kernel_launch(void* const* d_in, const int* in_sizes, int n_in,
                              void* d_out, int out_size, void* d_ws, size_t ws_size,
                              hipStream_t stream)
{
    const float* mp  = (const float*)d_in[0];
    const float* cp  = (const float*)d_in[1];
    const float* bp  = (const float*)d_in[2];
    const int*   seg = (const int*)d_in[3];
    const float* bg  = (const float*)d_in[4];
    float* out = (float*)d_out;

    char* ws = (char*)d_ws;
    float* probA = (float*)ws;
    unsigned* ctl    = (unsigned*)(ws + OFF_CTL);
    unsigned* hist   = ctl + CTL_HIST;
    unsigned* cnt1   = ctl + CTL_CNT1;
    unsigned* cnt2   = ctl + CTL_CNT2;
    unsigned* bar    = ctl + CTL_BAR;
    unsigned* flag   = ctl + CTL_FLAG;
    unsigned* prefix = ctl + CTL_PREFIX;
    unsigned* krem   = ctl + CTL_KREM;
    float*    thr    = (float*)(ctl + CTL_THR);
    float*    ppsum  = (float*)(ctl + CTL_PPSUM);
    unsigned* ppcnt  = ctl + CTL_PPCNT;
    float*    opsum  = (float*)(ctl + CTL_OPSUM);
    unsigned* opcnt  = ctl + CTL_OPCNT;
    float*    bps    = (float*)(ctl + CTL_BPS);
    unsigned* bpc    = ctl + CTL_BPC;

    // Zero hist-region counters (cnt1/cnt2), bar, flag in ONE stream-ordered
    // memset: ctl u32 [0, 24580) (hist is re-zeroed by the slow path itself;
    // zeroing it here is harmless).
    hipMemsetAsync(ws + OFF_CTL, 0, 24580ull * 4, stream);

    fused_pass1<<<dim3(GRID_P1), 256, 0, stream>>>(mp, cp, bp, seg, bg, probA,
                                                   ppsum, ppcnt, bps, bpc,
                                                   cnt1, cnt2, flag, out);
    finish_all<<<dim3(256), 256, 0, stream>>>(probA, seg, ppsum, ppcnt, bps, bpc,
                                              hist, bar, prefix, krem, thr,
                                              opsum, opcnt, flag, out);
}